// Round 1
// baseline (4484.055 us; speedup 1.0000x reference)
//
#include <hip/hip_runtime.h>
#include <cstdint>
#include <cstddef>

typedef unsigned short u16;
typedef unsigned int u32;
typedef __bf16 bf16x8 __attribute__((ext_vector_type(8)));
typedef float f32x4 __attribute__((ext_vector_type(4)));

__device__ inline float bf2f(u16 h){ union{u32 u; float f;} v; v.u = ((u32)h)<<16; return v.f; }
__device__ inline u16 f2bf(float f){ union{float f; u32 u;} v; v.f=f; u32 r = v.u + 0x7fffu + ((v.u>>16)&1u); return (u16)(r>>16); }

union V16 { uint4 u; bf16x8 b; };

// ---------------- block reduction helpers ----------------
__device__ inline float2 block_red_sum2(float a, float b){
  #pragma unroll
  for (int o=32;o;o>>=1){ a += __shfl_xor(a,o,64); b += __shfl_xor(b,o,64); }
  __shared__ float ta[4], tb[4];
  int w = threadIdx.x>>6;
  if ((threadIdx.x&63)==0){ ta[w]=a; tb[w]=b; }
  __syncthreads();
  float ra = ta[0]+ta[1]+ta[2]+ta[3];
  float rb = tb[0]+tb[1]+tb[2]+tb[3];
  __syncthreads();
  return make_float2(ra, rb);
}
__device__ inline float block_red_max(float a){
  #pragma unroll
  for (int o=32;o;o>>=1) a = fmaxf(a, __shfl_xor(a,o,64));
  __shared__ float tm[4];
  int w = threadIdx.x>>6;
  if ((threadIdx.x&63)==0) tm[w]=a;
  __syncthreads();
  float r = fmaxf(fmaxf(tm[0],tm[1]),fmaxf(tm[2],tm[3]));
  __syncthreads();
  return r;
}
__device__ inline float block_red_sum(float a){
  #pragma unroll
  for (int o=32;o;o>>=1) a += __shfl_xor(a,o,64);
  __shared__ float ts[4];
  int w = threadIdx.x>>6;
  if ((threadIdx.x&63)==0) ts[w]=a;
  __syncthreads();
  float r = ts[0]+ts[1]+ts[2]+ts[3];
  __syncthreads();
  return r;
}

// ---------------- MFMA GEMM: C = A[M,K](bf16) @ Bt[N,K](bf16)^T + epilogue ----------------
// 128x128 tile, BK=32, 256 threads = 4 waves (2x2 of 64x64, each 4x4 of 16x16x32 MFMA).
// flags: 1=+bias[col], 2=+temb[(row/rowdiv)*1280+col], 4=+res[row*ldres+col] (f32), 8=gelu, 16=bf16 out
__global__ __launch_bounds__(256) void kw_gemm(
    const u16* __restrict__ A, const u16* __restrict__ B, void* __restrict__ C,
    int M, int Nclamp, int Nout, int K, int lda, int ldb, int ldc,
    long long sA1, long long sA2, long long sB1, long long sB2, long long sC1, long long sC2,
    int zdiv, int flags,
    const float* __restrict__ bias, const float* __restrict__ temb, int rowdiv,
    const float* __restrict__ res, int ldres)
{
  int z = blockIdx.z;
  int z1 = z / zdiv, z2 = z - z1*zdiv;
  A += z1*sA1 + z2*sA2;
  B += z1*sB1 + z2*sB2;
  long long coff = z1*sC1 + z2*sC2;

  __shared__ u16 As[128][40];   // +8 pad: conflict-light b128 reads/writes
  __shared__ u16 Bs[128][40];

  int tid  = threadIdx.x;
  int lane = tid & 63, wave = tid >> 6;
  int wm = (wave >> 1) * 64, wn = (wave & 1) * 64;
  int lr = lane & 15, quad = lane >> 4;

  int rowBase = blockIdx.x * 128;
  int colBase = blockIdx.y * 128;

  int srow  = tid >> 2;        // 0..63
  int skseg = (tid & 3) * 8;   // 0,8,16,24

  int ar0 = min(rowBase + srow, M-1);
  int ar1 = min(rowBase + 64 + srow, M-1);
  int br0 = min(colBase + srow, Nclamp-1);
  int br1 = min(colBase + 64 + srow, Nclamp-1);
  const u16* ap0 = A + (long long)ar0*lda + skseg;
  const u16* ap1 = A + (long long)ar1*lda + skseg;
  const u16* bp0 = B + (long long)br0*ldb + skseg;
  const u16* bp1 = B + (long long)br1*ldb + skseg;

  f32x4 acc[4][4];
  #pragma unroll
  for (int mi=0; mi<4; mi++)
    #pragma unroll
    for (int ni=0; ni<4; ni++) acc[mi][ni] = (f32x4){0.f,0.f,0.f,0.f};

  for (int k0 = 0; k0 < K; k0 += 32) {
    uint4 a0 = *(const uint4*)ap0;
    uint4 a1 = *(const uint4*)ap1;
    uint4 b0 = *(const uint4*)bp0;
    uint4 b1 = *(const uint4*)bp1;
    __syncthreads();
    *(uint4*)&As[srow][skseg]    = a0;
    *(uint4*)&As[64+srow][skseg] = a1;
    *(uint4*)&Bs[srow][skseg]    = b0;
    *(uint4*)&Bs[64+srow][skseg] = b1;
    __syncthreads();

    V16 af[4], bf[4];
    #pragma unroll
    for (int mi=0; mi<4; mi++) af[mi].u = *(const uint4*)&As[wm + mi*16 + lr][quad*8];
    #pragma unroll
    for (int ni=0; ni<4; ni++) bf[ni].u = *(const uint4*)&Bs[wn + ni*16 + lr][quad*8];
    #pragma unroll
    for (int mi=0; mi<4; mi++)
      #pragma unroll
      for (int ni=0; ni<4; ni++)
        acc[mi][ni] = __builtin_amdgcn_mfma_f32_16x16x32_bf16(af[mi].b, bf[ni].b, acc[mi][ni], 0, 0, 0);

    ap0 += 32; ap1 += 32; bp0 += 32; bp1 += 32;
  }

  // epilogue
  #pragma unroll
  for (int mi=0; mi<4; mi++){
    #pragma unroll
    for (int ni=0; ni<4; ni++){
      #pragma unroll
      for (int rr=0; rr<4; rr++){
        int row = rowBase + wm + mi*16 + quad*4 + rr;
        int col = colBase + wn + ni*16 + lr;
        if (row < M && col < Nout){
          float x = acc[mi][ni][rr];
          if (flags & 1) x += bias[col];
          if (flags & 2) x += temb[(long long)(row/rowdiv)*1280 + col];
          if (flags & 4) x += res[(long long)row*ldres + col];
          if (flags & 8) x = 0.5f*x*(1.f + erff(x*0.70710678118654752f));
          long long o = coff + (long long)row*ldc + col;
          if (flags & 16) ((u16*)C)[o] = f2bf(x);
          else            ((float*)C)[o] = x;
        }
      }
    }
  }
}

// ---------------- transpose f32[K,N] -> bf16[N,K] ----------------
__global__ __launch_bounds__(256) void kw_transpose(const float* __restrict__ in, u16* __restrict__ out,
                                                    int K, int N)
{
  __shared__ u16 t[64][68];
  int k0 = blockIdx.x*64, n0 = blockIdx.y*64;
  int tid = threadIdx.x; int c = tid & 63; int r4 = tid >> 6;
  #pragma unroll
  for (int p = 0; p < 16; p++){
    int kr = r4 + p*4;
    t[kr][c] = f2bf(in[(long long)(k0+kr)*N + n0 + c]);
  }
  __syncthreads();
  #pragma unroll
  for (int p = 0; p < 16; p++){
    int nr = r4 + p*4;
    out[(long long)(n0+nr)*K + k0 + c] = t[c][nr];
  }
}

// ---------------- V transpose: kv[b,key,1280+h*64+d] -> Vt[bh, d, keypad672] ----------------
__global__ __launch_bounds__(256) void kw_vt(const u16* __restrict__ kv, u16* __restrict__ Vt)
{
  int z = blockIdx.x; int kt = blockIdx.y;
  int b = z / 20, hh = z - b*20;
  const u16* src = kv + (long long)b*641*2560 + 1280 + hh*64;
  u16* dst = Vt + (long long)z*64*672;
  __shared__ u16 t[64][68];
  int tid = threadIdx.x; int c = tid & 63; int r4 = tid >> 6;
  #pragma unroll
  for (int p = 0; p < 16; p++){
    int krow = r4 + p*4;
    int key = kt*64 + krow;
    t[krow][c] = (key < 641) ? src[(long long)key*2560 + c] : (u16)0;
  }
  __syncthreads();
  #pragma unroll
  for (int p = 0; p < 16; p++){
    int d = r4 + p*4;
    int key = kt*64 + c;
    if (key < 672) dst[(long long)d*672 + key] = t[c][d];
  }
}

// ---------------- softmax in-place over bf16 scores rows of 672 (valid 641), scale 1/8 ----------------
__global__ __launch_bounds__(256) void kw_softmax(u16* __restrict__ sc)
{
  u16* row = sc + (long long)blockIdx.x * 672;
  int tid = threadIdx.x;
  float v[3];
  float mx = -1e30f;
  #pragma unroll
  for (int i=0;i<3;i++){
    int c = tid + i*256;
    if (c < 641){ v[i] = bf2f(row[c])*0.125f; mx = fmaxf(mx, v[i]); } else v[i] = -1e30f;
  }
  float M = block_red_max(mx);
  float s = 0.f;
  #pragma unroll
  for (int i=0;i<3;i++){
    int c = tid + i*256;
    if (c < 641){ v[i] = __expf(v[i]-M); s += v[i]; }
  }
  float S = block_red_sum(s);
  float inv = 1.0f / S;
  #pragma unroll
  for (int i=0;i<3;i++){
    int c = tid + i*256;
    if (c < 672) row[c] = (c < 641) ? f2bf(v[i]*inv) : (u16)0;
  }
}

// ---------------- time embedding ----------------
__global__ void kw_timeproj(const float* __restrict__ tstep, float* __restrict__ tproj)
{
  int b = blockIdx.x; int j = threadIdx.x; // 320
  float t = tstep[b];
  int idx = (j < 160) ? j : (j - 160);
  float freq = expf(-9.210340371976184f * (float)idx / 160.0f);
  float a = t * freq;
  tproj[b*320 + j] = (j < 160) ? cosf(a) : sinf(a);
}

// small dense layer (f32): out[b,n] = act(in[b,:]@W + bias)
__global__ __launch_bounds__(256) void kw_mlp(const float* __restrict__ in, const float* __restrict__ W,
    const float* __restrict__ bias, float* __restrict__ out, int K, int N, int act,
    float* __restrict__ out_silu, float* __restrict__ out_copy)
{
  int b = blockIdx.x;
  int n = blockIdx.y*256 + threadIdx.x;
  const float* inr = in + (long long)b*K;
  float acc = bias[n];
  for (int k=0;k<K;k++) acc = fmaf(inr[k], W[(long long)k*N + n], acc);
  float sig = 1.f/(1.f+expf(-acc));
  out[(long long)b*N + n] = act ? acc*sig : acc;
  if (out_silu) out_silu[(long long)b*N + n] = acc*sig;
  if (out_copy) out_copy[(long long)b*N + n] = acc;
}

__global__ void kw_ada_init(const float* __restrict__ ada_b, float* __restrict__ ada)
{
  int idx = blockIdx.x*256 + threadIdx.x;
  if (idx < 4*32*5120){
    int i = idx / (32*5120);
    int j = idx % 5120;
    ada[idx] = ada_b[i*5120 + j];
  }
}

__global__ __launch_bounds__(256) void kw_ada(const float* __restrict__ silu_t,
    const float* __restrict__ adaW, float* __restrict__ ada)
{
  int jt = blockIdx.x, i = blockIdx.y, ks = blockIdx.z;
  int tid = threadIdx.x;
  int j = jt*256 + tid;
  __shared__ float sbuf[32][160];
  #pragma unroll
  for (int p = 0; p < 20; p++){
    int idx = tid + p*256;
    int b = idx / 160, k = idx - b*160;
    sbuf[b][k] = silu_t[b*1280 + ks*160 + k];
  }
  __syncthreads();
  float acc[32];
  #pragma unroll
  for (int b=0;b<32;b++) acc[b]=0.f;
  const float* wp = adaW + ((long long)i*1280 + ks*160)*5120 + j;
  for (int k=0;k<160;k++){
    float w = wp[(long long)k*5120];
    #pragma unroll
    for (int b=0;b<32;b++) acc[b] = fmaf(sbuf[b][k], w, acc[b]);
  }
  float* op = ada + (long long)i*32*5120 + j;
  for (int b=0;b<32;b++) atomicAdd(op + (long long)b*5120, acc[b]);
}

__global__ void kw_init_lat(const float* __restrict__ l0, float* __restrict__ lat)
{
  int r = blockIdx.x; int q = r & 63;
  #pragma unroll
  for (int i=0;i<5;i++){
    int c = threadIdx.x + i*256;
    lat[(long long)r*1280 + c] = l0[q*1280 + c];
  }
}

__global__ void kw_cvt(const float* __restrict__ in, u16* __restrict__ out, long long n4)
{
  long long i = ((long long)blockIdx.x*256 + threadIdx.x);
  if (i < n4){
    float4 v = *(const float4*)(in + i*4);
    u32 lo = (u32)f2bf(v.x) | ((u32)f2bf(v.y)<<16);
    u32 hi = (u32)f2bf(v.z) | ((u32)f2bf(v.w)<<16);
    uint2 o; o.x = lo; o.y = hi;
    *(uint2*)(out + i*4) = o;
  }
}

// LN over H=1280, bf16 in -> bf16 out into cat[b*641 + (r%577)]
__global__ __launch_bounds__(256) void kw_ln_x(const u16* __restrict__ h, u16* __restrict__ cat,
    const float* __restrict__ g, const float* __restrict__ bb)
{
  int r = blockIdx.x;
  int batch = r / 577; int rr = r - batch*577;
  const u16* row = h + (long long)r*1280;
  u16* orow = cat + ((long long)batch*641 + rr)*1280;
  int tid = threadIdx.x;
  float v[5]; float s=0.f, s2=0.f;
  #pragma unroll
  for (int i=0;i<5;i++){ float x = bf2f(row[tid+i*256]); v[i]=x; s+=x; s2+=x*x; }
  float2 r2 = block_red_sum2(s, s2);
  float mean = r2.x * (1.f/1280.f);
  float var  = r2.y * (1.f/1280.f) - mean*mean;
  float rstd = rsqrtf(var + 1e-5f);
  #pragma unroll
  for (int i=0;i<5;i++){
    int c = tid+i*256;
    orow[c] = f2bf((v[i]-mean)*rstd*g[c] + bb[c]);
  }
}

// LN over H=1280, f32 in, * (1+sc)+sh, bf16 out (+ optional copy into cat at row b*641+577+q)
__global__ __launch_bounds__(256) void kw_ln_mod(const float* __restrict__ lat, u16* __restrict__ out1,
    u16* __restrict__ cat, const float* __restrict__ g, const float* __restrict__ bb,
    const float* __restrict__ adabase)
{
  int r = blockIdx.x;
  int b = r >> 6, q = r & 63;
  const float* row = lat + (long long)r*1280;
  const float* ab = adabase + (long long)b*5120;
  int tid = threadIdx.x;
  float v[5]; float s=0.f, s2=0.f;
  #pragma unroll
  for (int i=0;i<5;i++){ float x = row[tid+i*256]; v[i]=x; s+=x; s2+=x*x; }
  float2 r2 = block_red_sum2(s, s2);
  float mean = r2.x * (1.f/1280.f);
  float var  = r2.y * (1.f/1280.f) - mean*mean;
  float rstd = rsqrtf(var + 1e-5f);
  #pragma unroll
  for (int i=0;i<5;i++){
    int c = tid+i*256;
    float sh = ab[c], sc = ab[1280+c];
    float y = ((v[i]-mean)*rstd*g[c] + bb[c])*(1.f+sc) + sh;
    u16 o = f2bf(y);
    out1[(long long)r*1280 + c] = o;
    if (cat) cat[((long long)b*641 + 577 + q)*1280 + c] = o;
  }
}

// final LN over O=2432, f32 in -> f32 out
__global__ __launch_bounds__(256) void kw_ln_out(const float* __restrict__ in, float* __restrict__ out,
    const float* __restrict__ g, const float* __restrict__ bb)
{
  int r = blockIdx.x;
  const float* row = in + (long long)r*2432;
  int tid = threadIdx.x;
  float v[10]; float s=0.f, s2=0.f;
  #pragma unroll
  for (int i=0;i<10;i++){
    int c = tid + i*256;
    float x = (c < 2432) ? row[c] : 0.f;
    v[i]=x; s+=x; s2+=x*x;
  }
  float2 r2 = block_red_sum2(s, s2);
  float mean = r2.x * (1.f/2432.f);
  float var  = r2.y * (1.f/2432.f) - mean*mean;
  float rstd = rsqrtf(var + 1e-5f);
  #pragma unroll
  for (int i=0;i<10;i++){
    int c = tid + i*256;
    if (c < 2432) out[(long long)r*2432 + c] = (v[i]-mean)*rstd*g[c] + bb[c];
  }
}

// ---------------- host ----------------
static inline void launch_gemm(hipStream_t s, const u16* A, const u16* B, void* C,
    int M, int Nclamp, int Nout, int K, int lda, int ldb, int ldc,
    int nz, int zdiv, long long sA1, long long sA2, long long sB1, long long sB2,
    long long sC1, long long sC2, int flags,
    const float* bias = nullptr, const float* temb = nullptr, int rowdiv = 1,
    const float* res = nullptr, int ldres = 0)
{
  dim3 g((M+127)/128, (Nout+127)/128, nz);
  kw_gemm<<<g, dim3(256), 0, s>>>(A,B,C,M,Nclamp,Nout,K,lda,ldb,ldc,
      sA1,sA2,sB1,sB2,sC1,sC2,zdiv,flags,bias,temb,rowdiv,res,ldres);
}

extern "C" void kernel_launch(void* const* d_in, const int* in_sizes, int n_in,
                              void* d_out, int out_size, void* d_ws, size_t ws_size,
                              hipStream_t stream)
{
  const float* x         = (const float*)d_in[0];
  const float* timestep  = (const float*)d_in[1];
  const float* latents0  = (const float*)d_in[2];
  const float* proj_in_W = (const float*)d_in[3];
  const float* proj_in_b = (const float*)d_in[4];
  const float* te1_W     = (const float*)d_in[5];
  const float* te1_b     = (const float*)d_in[6];
  const float* te2_W     = (const float*)d_in[7];
  const float* te2_b     = (const float*)d_in[8];
  const float* ln0_g     = (const float*)d_in[9];
  const float* ln0_b     = (const float*)d_in[10];
  const float* ln1_g     = (const float*)d_in[11];
  const float* ln1_b     = (const float*)d_in[12];
  const float* Wq        = (const float*)d_in[13];
  const float* Wkv       = (const float*)d_in[14];
  const float* Wo        = (const float*)d_in[15];
  const float* ada_W     = (const float*)d_in[16];
  const float* ada_b     = (const float*)d_in[17];
  const float* lnada_g   = (const float*)d_in[18];
  const float* lnada_b   = (const float*)d_in[19];
  const float* Wff1      = (const float*)d_in[20];
  const float* Wff2      = (const float*)d_in[21];
  const float* proj_out_W= (const float*)d_in[22];
  const float* proj_out_b= (const float*)d_in[23];
  const float* norm_out_g= (const float*)d_in[24];
  const float* norm_out_b= (const float*)d_in[25];
  float* out = (float*)d_out;

  const long long MX = 18464;   // B*N
  const long long MC = 20512;   // B*641

  char* w = (char*)d_ws; size_t off = 0;
  auto alloc = [&](size_t bytes)->void*{ void* p = w + off; off += (bytes + 255) & ~(size_t)255; return p; };

  float* tproj  = (float*)alloc(32*320*4);
  float* hidden = (float*)alloc(32*1280*4);
  float* temb   = (float*)alloc(32*1280*4);
  float* silu_t = (float*)alloc(32*1280*4);
  float* ada    = (float*)alloc(4*32*5120*4);
  u16*  h    = (u16*)alloc(MX*1280*2);
  u16*  cat  = (u16*)alloc(MC*1280*2);
  u16*  lm   = (u16*)alloc(2048*1280*2);
  u16*  lm2  = (u16*)alloc(2048*1280*2);
  u16*  qb   = (u16*)alloc(2048*1280*2);
  u16*  att  = (u16*)alloc(2048*1280*2);
  float* lat = (float*)alloc(2048*1280*4);
  u16*  kvb  = (u16*)alloc(MC*2560*2);
  u16*  Vt   = (u16*)alloc((long long)640*64*672*2);
  u16*  WT_pi  = (u16*)alloc(1280*1152*2);
  u16*  WT_po  = (u16*)alloc((long long)2432*1280*2);
  u16*  WqT    = (u16*)alloc(1280*1280*2);
  u16*  WkvT   = (u16*)alloc(2560*1280*2);
  u16*  WoT    = (u16*)alloc(1280*1280*2);
  u16*  Wff1T  = (u16*)alloc((long long)5120*1280*2);
  u16*  Wff2T  = (u16*)alloc((long long)1280*5120*2);
  // overlaid region: x_bf16 -> (scores/P alternating with ffh) -> proj_out pre-LN
  char* R = (char*)alloc((long long)640*64*672*2);
  u16*  xbf    = (u16*)R;
  u16*  scores = (u16*)R;
  u16*  ffh    = (u16*)R;
  float* po    = (float*)R;

  if (off > ws_size) return; // workspace too small -> fail loudly via wrong output

  // time embedding MLP (f32, exact path: t_emb is output 1)
  kw_timeproj<<<dim3(32), dim3(320), 0, stream>>>(timestep, tproj);
  kw_mlp<<<dim3(32,5), dim3(256), 0, stream>>>(tproj, te1_W, te1_b, hidden, 320, 1280, 1, nullptr, nullptr);
  kw_mlp<<<dim3(32,5), dim3(256), 0, stream>>>(hidden, te2_W, te2_b, temb, 1280, 1280, 0, silu_t,
                                               out + (long long)2048*2432);
  // adaLN embeddings for all 4 blocks
  kw_ada_init<<<dim3(2560), dim3(256), 0, stream>>>(ada_b, ada);
  kw_ada<<<dim3(20,4,8), dim3(256), 0, stream>>>(silu_t, ada_W, ada);

  // proj_in
  kw_cvt<<<dim3((unsigned)((MX*1152/4 + 255)/256)), dim3(256), 0, stream>>>(x, xbf, MX*1152/4);
  kw_transpose<<<dim3(18,20), dim3(256), 0, stream>>>(proj_in_W, WT_pi, 1152, 1280);
  launch_gemm(stream, xbf, WT_pi, h, (int)MX, 1280, 1280, 1152, 1152, 1152, 1280,
              1, 1, 0,0,0,0,0,0, 1|2|16, proj_in_b, temb, 577);

  kw_init_lat<<<dim3(2048), dim3(256), 0, stream>>>(latents0, lat);
  kw_transpose<<<dim3(20,38), dim3(256), 0, stream>>>(proj_out_W, WT_po, 1280, 2432);

  for (int i = 0; i < 4; i++){
    kw_transpose<<<dim3(20,20), dim3(256), 0, stream>>>(Wq   + (long long)i*1280*1280, WqT,   1280, 1280);
    kw_transpose<<<dim3(20,40), dim3(256), 0, stream>>>(Wkv  + (long long)i*1280*2560, WkvT,  1280, 2560);
    kw_transpose<<<dim3(20,20), dim3(256), 0, stream>>>(Wo   + (long long)i*1280*1280, WoT,   1280, 1280);
    kw_transpose<<<dim3(20,80), dim3(256), 0, stream>>>(Wff1 + (long long)i*1280*5120, Wff1T, 1280, 5120);
    kw_transpose<<<dim3(80,20), dim3(256), 0, stream>>>(Wff2 + (long long)i*5120*1280, Wff2T, 5120, 1280);

    kw_ln_x<<<dim3((unsigned)MX), dim3(256), 0, stream>>>(h, cat, ln0_g + i*1280, ln0_b + i*1280);
    kw_ln_mod<<<dim3(2048), dim3(256), 0, stream>>>(lat, lm, cat, ln1_g + i*1280, ln1_b + i*1280,
                                                    ada + (long long)i*32*5120 + 0);
    // q / kv projections
    launch_gemm(stream, lm,  WqT,  qb,  2048, 1280, 1280, 1280, 1280, 1280, 1280, 1, 1, 0,0,0,0,0,0, 16);
    launch_gemm(stream, cat, WkvT, kvb, (int)MC, 2560, 2560, 1280, 1280, 1280, 2560, 1, 1, 0,0,0,0,0,0, 16);
    // attention: scores = (Q Kt)/8, softmax, att = P V
    launch_gemm(stream, qb, kvb, scores, 64, 641, 672, 64, 1280, 2560, 672,
                640, 20, 81920, 64, 1640960, 64, 860160, 43008, 16);
    kw_softmax<<<dim3(40960), dim3(256), 0, stream>>>(scores);
    kw_vt<<<dim3(640,11), dim3(256), 0, stream>>>(kvb, Vt);
    launch_gemm(stream, scores, Vt, att, 64, 64, 64, 672, 672, 672, 1280,
                640, 20, 860160, 43008, 860160, 43008, 81920, 64, 16);
    // out projection + residual (in-place on lat)
    launch_gemm(stream, att, WoT, lat, 2048, 1280, 1280, 1280, 1280, 1280, 1280,
                1, 1, 0,0,0,0,0,0, 4, nullptr, nullptr, 1, lat, 1280);
    // MLP
    kw_ln_mod<<<dim3(2048), dim3(256), 0, stream>>>(lat, lm2, nullptr, lnada_g + i*1280, lnada_b + i*1280,
                                                    ada + (long long)i*32*5120 + 2560);
    launch_gemm(stream, lm2, Wff1T, ffh, 2048, 5120, 5120, 1280, 1280, 1280, 5120,
                1, 1, 0,0,0,0,0,0, 8|16);
    launch_gemm(stream, ffh, Wff2T, lat, 2048, 1280, 1280, 5120, 5120, 5120, 1280,
                1, 1, 0,0,0,0,0,0, 4, nullptr, nullptr, 1, lat, 1280);
  }

  // proj_out + final LN
  kw_cvt<<<dim3(2560), dim3(256), 0, stream>>>(lat, lm, 2048*1280/4);
  launch_gemm(stream, lm, WT_po, po, 2048, 2432, 2432, 1280, 1280, 1280, 2432,
              1, 1, 0,0,0,0,0,0, 1, proj_out_b);
  kw_ln_out<<<dim3(2048), dim3(256), 0, stream>>>(po, out, norm_out_g, norm_out_b);
}

// Round 2
// 3984.690 us; speedup vs baseline: 1.1253x; 1.1253x over previous
//
#include <hip/hip_runtime.h>
#include <cstdint>
#include <cstddef>

typedef unsigned short u16;
typedef unsigned int u32;
typedef __bf16 bf16x8 __attribute__((ext_vector_type(8)));
typedef float f32x4 __attribute__((ext_vector_type(4)));

__device__ inline float bf2f(u16 h){ union{u32 u; float f;} v; v.u = ((u32)h)<<16; return v.f; }
__device__ inline u16 f2bf(float f){ union{float f; u32 u;} v; v.f=f; u32 r = v.u + 0x7fffu + ((v.u>>16)&1u); return (u16)(r>>16); }

union V16 { uint4 u; bf16x8 b; };

// direct global->LDS, 16B per lane; LDS dest = wave-uniform base + lane*16
__device__ inline void gll16(const u16* g, u16* l){
  __builtin_amdgcn_global_load_lds(
      (const __attribute__((address_space(1))) u32*)g,
      (__attribute__((address_space(3))) u32*)l,
      16, 0, 0);
}

// ---------------- block reduction helpers ----------------
__device__ inline float2 block_red_sum2(float a, float b){
  #pragma unroll
  for (int o=32;o;o>>=1){ a += __shfl_xor(a,o,64); b += __shfl_xor(b,o,64); }
  __shared__ float ta[4], tb[4];
  int w = threadIdx.x>>6;
  if ((threadIdx.x&63)==0){ ta[w]=a; tb[w]=b; }
  __syncthreads();
  float ra = ta[0]+ta[1]+ta[2]+ta[3];
  float rb = tb[0]+tb[1]+tb[2]+tb[3];
  __syncthreads();
  return make_float2(ra, rb);
}
__device__ inline float block_red_max(float a){
  #pragma unroll
  for (int o=32;o;o>>=1) a = fmaxf(a, __shfl_xor(a,o,64));
  __shared__ float tm[4];
  int w = threadIdx.x>>6;
  if ((threadIdx.x&63)==0) tm[w]=a;
  __syncthreads();
  float r = fmaxf(fmaxf(tm[0],tm[1]),fmaxf(tm[2],tm[3]));
  __syncthreads();
  return r;
}
__device__ inline float block_red_sum(float a){
  #pragma unroll
  for (int o=32;o;o>>=1) a += __shfl_xor(a,o,64);
  __shared__ float ts[4];
  int w = threadIdx.x>>6;
  if ((threadIdx.x&63)==0) ts[w]=a;
  __syncthreads();
  float r = ts[0]+ts[1]+ts[2]+ts[3];
  __syncthreads();
  return r;
}

// ---------------- MFMA GEMM: C = A[M,K](bf16) @ Bt[N,K](bf16)^T + epilogue ----------------
// 128x128 tile, BK=32, 256 threads = 4 waves (2x2 of 64x64, each 4x4 of 16x16x32 MFMA).
// m97 structure: global_load_lds width-16 staging, unpadded LDS [128][32], 2-barrier K-loop.
// flags: 1=+bias[col], 2=+temb[(row/rowdiv)*1280+col], 4=+res[row*ldres+col] (f32), 8=gelu, 16=bf16 out
__global__ __launch_bounds__(256) void kw_gemm(
    const u16* __restrict__ A, const u16* __restrict__ B, void* __restrict__ C,
    int M, int Nclamp, int Nout, int K, int lda, int ldb, int ldc,
    long long sA1, long long sA2, long long sB1, long long sB2, long long sC1, long long sC2,
    int zdiv, int flags,
    const float* __restrict__ bias, const float* __restrict__ temb, int rowdiv,
    const float* __restrict__ res, int ldres)
{
  int z = blockIdx.z;
  int z1 = z / zdiv, z2 = z - z1*zdiv;
  A += z1*sA1 + z2*sA2;
  B += z1*sB1 + z2*sB2;
  long long coff = z1*sC1 + z2*sC2;

  __shared__ u16 As[128*32];   // unpadded: layout dictated by global_load_lds deposit order
  __shared__ u16 Bs[128*32];

  int tid  = threadIdx.x;
  int lane = tid & 63, wave = tid >> 6;
  int wm = (wave >> 1) * 64, wn = (wave & 1) * 64;
  int lr = lane & 15, quad = lane >> 4;

  int rowBase = blockIdx.x * 128;
  int colBase = blockIdx.y * 128;

  // staging map: wave w, lane l -> row w*16 + l/4, k-seg (l%4)*8  (16B per lane)
  int srow = wave*16 + (lane >> 2);
  int sseg = (lane & 3) * 8;

  int ar0 = min(rowBase + srow, M-1);
  int ar1 = min(rowBase + 64 + srow, M-1);
  int br0 = min(colBase + srow, Nclamp-1);
  int br1 = min(colBase + 64 + srow, Nclamp-1);
  const u16* ap0 = A + (long long)ar0*lda + sseg;
  const u16* ap1 = A + (long long)ar1*lda + sseg;
  const u16* bp0 = B + (long long)br0*ldb + sseg;
  const u16* bp1 = B + (long long)br1*ldb + sseg;

  u16* lA0 = As + wave*512;          // rows wave*16 .. +15
  u16* lA1 = As + 2048 + wave*512;   // rows 64+wave*16 .. +15
  u16* lB0 = Bs + wave*512;
  u16* lB1 = Bs + 2048 + wave*512;

  f32x4 acc[4][4];
  #pragma unroll
  for (int mi=0; mi<4; mi++)
    #pragma unroll
    for (int ni=0; ni<4; ni++) acc[mi][ni] = (f32x4){0.f,0.f,0.f,0.f};

  for (int k0 = 0; k0 < K; k0 += 32) {
    gll16(ap0, lA0);
    gll16(ap1, lA1);
    gll16(bp0, lB0);
    gll16(bp1, lB1);
    __syncthreads();   // vmcnt drain + visibility

    V16 af[4], bf[4];
    #pragma unroll
    for (int mi=0; mi<4; mi++) af[mi].u = *(const uint4*)&As[(wm + mi*16 + lr)*32 + quad*8];
    #pragma unroll
    for (int ni=0; ni<4; ni++) bf[ni].u = *(const uint4*)&Bs[(wn + ni*16 + lr)*32 + quad*8];
    #pragma unroll
    for (int mi=0; mi<4; mi++)
      #pragma unroll
      for (int ni=0; ni<4; ni++)
        acc[mi][ni] = __builtin_amdgcn_mfma_f32_16x16x32_bf16(af[mi].b, bf[ni].b, acc[mi][ni], 0, 0, 0);

    __syncthreads();   // all reads done before next overwrite
    ap0 += 32; ap1 += 32; bp0 += 32; bp1 += 32;
  }

  // epilogue
  #pragma unroll
  for (int mi=0; mi<4; mi++){
    #pragma unroll
    for (int ni=0; ni<4; ni++){
      #pragma unroll
      for (int rr=0; rr<4; rr++){
        int row = rowBase + wm + mi*16 + quad*4 + rr;
        int col = colBase + wn + ni*16 + lr;
        if (row < M && col < Nout){
          float x = acc[mi][ni][rr];
          if (flags & 1) x += bias[col];
          if (flags & 2) x += temb[(long long)(row/rowdiv)*1280 + col];
          if (flags & 4) x += res[(long long)row*ldres + col];
          if (flags & 8) x = 0.5f*x*(1.f + erff(x*0.70710678118654752f));
          long long o = coff + (long long)row*ldc + col;
          if (flags & 16) ((u16*)C)[o] = f2bf(x);
          else            ((float*)C)[o] = x;
        }
      }
    }
  }
}

// ---------------- transpose f32[K,N] -> bf16[N,K] ----------------
__global__ __launch_bounds__(256) void kw_transpose(const float* __restrict__ in, u16* __restrict__ out,
                                                    int K, int N)
{
  __shared__ u16 t[64][68];
  int k0 = blockIdx.x*64, n0 = blockIdx.y*64;
  int tid = threadIdx.x; int c = tid & 63; int r4 = tid >> 6;
  #pragma unroll
  for (int p = 0; p < 16; p++){
    int kr = r4 + p*4;
    t[kr][c] = f2bf(in[(long long)(k0+kr)*N + n0 + c]);
  }
  __syncthreads();
  #pragma unroll
  for (int p = 0; p < 16; p++){
    int nr = r4 + p*4;
    out[(long long)(n0+nr)*K + k0 + c] = t[c][nr];
  }
}

// ---------------- V transpose: kv[b,key,1280+h*64+d] -> Vt[bh, d, keypad672] ----------------
__global__ __launch_bounds__(256) void kw_vt(const u16* __restrict__ kv, u16* __restrict__ Vt)
{
  int z = blockIdx.x; int kt = blockIdx.y;
  int b = z / 20, hh = z - b*20;
  const u16* src = kv + (long long)b*641*2560 + 1280 + hh*64;
  u16* dst = Vt + (long long)z*64*672;
  __shared__ u16 t[64][68];
  int tid = threadIdx.x; int c = tid & 63; int r4 = tid >> 6;
  #pragma unroll
  for (int p = 0; p < 16; p++){
    int krow = r4 + p*4;
    int key = kt*64 + krow;
    t[krow][c] = (key < 641) ? src[(long long)key*2560 + c] : (u16)0;
  }
  __syncthreads();
  #pragma unroll
  for (int p = 0; p < 16; p++){
    int d = r4 + p*4;
    int key = kt*64 + c;
    if (key < 672) dst[(long long)d*672 + key] = t[c][d];
  }
}

// ---------------- softmax in-place over bf16 scores rows of 672 (valid 641), scale 1/8 ----------------
__global__ __launch_bounds__(256) void kw_softmax(u16* __restrict__ sc)
{
  u16* row = sc + (long long)blockIdx.x * 672;
  int tid = threadIdx.x;
  float v[3];
  float mx = -1e30f;
  #pragma unroll
  for (int i=0;i<3;i++){
    int c = tid + i*256;
    if (c < 641){ v[i] = bf2f(row[c])*0.125f; mx = fmaxf(mx, v[i]); } else v[i] = -1e30f;
  }
  float M = block_red_max(mx);
  float s = 0.f;
  #pragma unroll
  for (int i=0;i<3;i++){
    int c = tid + i*256;
    if (c < 641){ v[i] = __expf(v[i]-M); s += v[i]; }
  }
  float S = block_red_sum(s);
  float inv = 1.0f / S;
  #pragma unroll
  for (int i=0;i<3;i++){
    int c = tid + i*256;
    if (c < 672) row[c] = (c < 641) ? f2bf(v[i]*inv) : (u16)0;
  }
}

// ---------------- time embedding ----------------
__global__ void kw_timeproj(const float* __restrict__ tstep, float* __restrict__ tproj)
{
  int b = blockIdx.x; int j = threadIdx.x; // 320
  float t = tstep[b];
  int idx = (j < 160) ? j : (j - 160);
  float freq = expf(-9.210340371976184f * (float)idx / 160.0f);
  float a = t * freq;
  tproj[b*320 + j] = (j < 160) ? cosf(a) : sinf(a);
}

// broadcast bias into out[32,N]
__global__ void kw_bias_bcast(const float* __restrict__ bias, float* __restrict__ out, int N)
{
  int b = blockIdx.x; int n = blockIdx.y*256 + threadIdx.x;
  if (n < N) out[(long long)b*N + n] = bias[n];
}

// dense layer, W-read-once k-split: out[b,n] += sum_k in[b,k0+k] * W[k0+k, n]  (atomic)
__global__ __launch_bounds__(256) void kw_mlp2(const float* __restrict__ in, const float* __restrict__ W,
    float* __restrict__ out, int K, int N, int kc)
{
  int n = blockIdx.x*256 + threadIdx.x;
  int k0 = blockIdx.y * kc;
  __shared__ float sbuf[32*160];
  for (int idx = threadIdx.x; idx < 32*kc; idx += 256){
    int b = idx / kc, k = idx - b*kc;
    sbuf[idx] = in[(long long)b*K + k0 + k];
  }
  __syncthreads();
  float acc[32];
  #pragma unroll
  for (int b=0;b<32;b++) acc[b]=0.f;
  const float* wp = W + (long long)k0*N + n;
  for (int k=0;k<kc;k++){
    float wv = wp[(long long)k*N];
    #pragma unroll
    for (int b=0;b<32;b++) acc[b] = fmaf(sbuf[b*kc+k], wv, acc[b]);
  }
  #pragma unroll
  for (int b=0;b<32;b++) atomicAdd(out + (long long)b*N + n, acc[b]);
}

__global__ void kw_silu_ip(float* __restrict__ p, int n)
{
  int i = blockIdx.x*256 + threadIdx.x;
  if (i < n){ float x = p[i]; p[i] = x/(1.f+expf(-x)); }
}

// silu_t = silu(temb); copy temb -> t_emb output
__global__ void kw_post_temb(const float* __restrict__ temb, float* __restrict__ silu_t,
                             float* __restrict__ tout, int n)
{
  int i = blockIdx.x*256 + threadIdx.x;
  if (i < n){
    float x = temb[i];
    silu_t[i] = x/(1.f+expf(-x));
    tout[i] = x;
  }
}

__global__ void kw_ada_init(const float* __restrict__ ada_b, float* __restrict__ ada)
{
  int idx = blockIdx.x*256 + threadIdx.x;
  if (idx < 4*32*5120){
    int i = idx / (32*5120);
    int j = idx % 5120;
    ada[idx] = ada_b[i*5120 + j];
  }
}

__global__ __launch_bounds__(256) void kw_ada(const float* __restrict__ silu_t,
    const float* __restrict__ adaW, float* __restrict__ ada)
{
  int jt = blockIdx.x, i = blockIdx.y, ks = blockIdx.z;
  int tid = threadIdx.x;
  int j = jt*256 + tid;
  __shared__ float sbuf[32][160];
  #pragma unroll
  for (int p = 0; p < 20; p++){
    int idx = tid + p*256;
    int b = idx / 160, k = idx - b*160;
    sbuf[b][k] = silu_t[b*1280 + ks*160 + k];
  }
  __syncthreads();
  float acc[32];
  #pragma unroll
  for (int b=0;b<32;b++) acc[b]=0.f;
  const float* wp = adaW + ((long long)i*1280 + ks*160)*5120 + j;
  for (int k=0;k<160;k++){
    float w = wp[(long long)k*5120];
    #pragma unroll
    for (int b=0;b<32;b++) acc[b] = fmaf(sbuf[b][k], w, acc[b]);
  }
  float* op = ada + (long long)i*32*5120 + j;
  for (int b=0;b<32;b++) atomicAdd(op + (long long)b*5120, acc[b]);
}

__global__ void kw_init_lat(const float* __restrict__ l0, float* __restrict__ lat)
{
  int r = blockIdx.x; int q = r & 63;
  #pragma unroll
  for (int i=0;i<5;i++){
    int c = threadIdx.x + i*256;
    lat[(long long)r*1280 + c] = l0[q*1280 + c];
  }
}

__global__ void kw_cvt(const float* __restrict__ in, u16* __restrict__ out, long long n4)
{
  long long i = ((long long)blockIdx.x*256 + threadIdx.x);
  if (i < n4){
    float4 v = *(const float4*)(in + i*4);
    u32 lo = (u32)f2bf(v.x) | ((u32)f2bf(v.y)<<16);
    u32 hi = (u32)f2bf(v.z) | ((u32)f2bf(v.w)<<16);
    uint2 o; o.x = lo; o.y = hi;
    *(uint2*)(out + i*4) = o;
  }
}

// LN over H=1280, bf16 in -> bf16 out into cat[b*641 + (r%577)]
__global__ __launch_bounds__(256) void kw_ln_x(const u16* __restrict__ h, u16* __restrict__ cat,
    const float* __restrict__ g, const float* __restrict__ bb)
{
  int r = blockIdx.x;
  int batch = r / 577; int rr = r - batch*577;
  const u16* row = h + (long long)r*1280;
  u16* orow = cat + ((long long)batch*641 + rr)*1280;
  int tid = threadIdx.x;
  float v[5]; float s=0.f, s2=0.f;
  #pragma unroll
  for (int i=0;i<5;i++){ float x = bf2f(row[tid+i*256]); v[i]=x; s+=x; s2+=x*x; }
  float2 r2 = block_red_sum2(s, s2);
  float mean = r2.x * (1.f/1280.f);
  float var  = r2.y * (1.f/1280.f) - mean*mean;
  float rstd = rsqrtf(var + 1e-5f);
  #pragma unroll
  for (int i=0;i<5;i++){
    int c = tid+i*256;
    orow[c] = f2bf((v[i]-mean)*rstd*g[c] + bb[c]);
  }
}

// LN over H=1280, f32 in, * (1+sc)+sh, bf16 out (+ optional copy into cat at row b*641+577+q)
__global__ __launch_bounds__(256) void kw_ln_mod(const float* __restrict__ lat, u16* __restrict__ out1,
    u16* __restrict__ cat, const float* __restrict__ g, const float* __restrict__ bb,
    const float* __restrict__ adabase)
{
  int r = blockIdx.x;
  int b = r >> 6, q = r & 63;
  const float* row = lat + (long long)r*1280;
  const float* ab = adabase + (long long)b*5120;
  int tid = threadIdx.x;
  float v[5]; float s=0.f, s2=0.f;
  #pragma unroll
  for (int i=0;i<5;i++){ float x = row[tid+i*256]; v[i]=x; s+=x; s2+=x*x; }
  float2 r2 = block_red_sum2(s, s2);
  float mean = r2.x * (1.f/1280.f);
  float var  = r2.y * (1.f/1280.f) - mean*mean;
  float rstd = rsqrtf(var + 1e-5f);
  #pragma unroll
  for (int i=0;i<5;i++){
    int c = tid+i*256;
    float sh = ab[c], sc = ab[1280+c];
    float y = ((v[i]-mean)*rstd*g[c] + bb[c])*(1.f+sc) + sh;
    u16 o = f2bf(y);
    out1[(long long)r*1280 + c] = o;
    if (cat) cat[((long long)b*641 + 577 + q)*1280 + c] = o;
  }
}

// final LN over O=2432, f32 in -> f32 out
__global__ __launch_bounds__(256) void kw_ln_out(const float* __restrict__ in, float* __restrict__ out,
    const float* __restrict__ g, const float* __restrict__ bb)
{
  int r = blockIdx.x;
  const float* row = in + (long long)r*2432;
  int tid = threadIdx.x;
  float v[10]; float s=0.f, s2=0.f;
  #pragma unroll
  for (int i=0;i<10;i++){
    int c = tid + i*256;
    float x = (c < 2432) ? row[c] : 0.f;
    v[i]=x; s+=x; s2+=x*x;
  }
  float2 r2 = block_red_sum2(s, s2);
  float mean = r2.x * (1.f/2432.f);
  float var  = r2.y * (1.f/2432.f) - mean*mean;
  float rstd = rsqrtf(var + 1e-5f);
  #pragma unroll
  for (int i=0;i<10;i++){
    int c = tid + i*256;
    if (c < 2432) out[(long long)r*2432 + c] = (v[i]-mean)*rstd*g[c] + bb[c];
  }
}

// ---------------- host ----------------
static inline void launch_gemm(hipStream_t s, const u16* A, const u16* B, void* C,
    int M, int Nclamp, int Nout, int K, int lda, int ldb, int ldc,
    int nz, int zdiv, long long sA1, long long sA2, long long sB1, long long sB2,
    long long sC1, long long sC2, int flags,
    const float* bias = nullptr, const float* temb = nullptr, int rowdiv = 1,
    const float* res = nullptr, int ldres = 0)
{
  dim3 g((M+127)/128, (Nout+127)/128, nz);
  kw_gemm<<<g, dim3(256), 0, s>>>(A,B,C,M,Nclamp,Nout,K,lda,ldb,ldc,
      sA1,sA2,sB1,sB2,sC1,sC2,zdiv,flags,bias,temb,rowdiv,res,ldres);
}

extern "C" void kernel_launch(void* const* d_in, const int* in_sizes, int n_in,
                              void* d_out, int out_size, void* d_ws, size_t ws_size,
                              hipStream_t stream)
{
  const float* x         = (const float*)d_in[0];
  const float* timestep  = (const float*)d_in[1];
  const float* latents0  = (const float*)d_in[2];
  const float* proj_in_W = (const float*)d_in[3];
  const float* proj_in_b = (const float*)d_in[4];
  const float* te1_W     = (const float*)d_in[5];
  const float* te1_b     = (const float*)d_in[6];
  const float* te2_W     = (const float*)d_in[7];
  const float* te2_b     = (const float*)d_in[8];
  const float* ln0_g     = (const float*)d_in[9];
  const float* ln0_b     = (const float*)d_in[10];
  const float* ln1_g     = (const float*)d_in[11];
  const float* ln1_b     = (const float*)d_in[12];
  const float* Wq        = (const float*)d_in[13];
  const float* Wkv       = (const float*)d_in[14];
  const float* Wo        = (const float*)d_in[15];
  const float* ada_W     = (const float*)d_in[16];
  const float* ada_b     = (const float*)d_in[17];
  const float* lnada_g   = (const float*)d_in[18];
  const float* lnada_b   = (const float*)d_in[19];
  const float* Wff1      = (const float*)d_in[20];
  const float* Wff2      = (const float*)d_in[21];
  const float* proj_out_W= (const float*)d_in[22];
  const float* proj_out_b= (const float*)d_in[23];
  const float* norm_out_g= (const float*)d_in[24];
  const float* norm_out_b= (const float*)d_in[25];
  float* out = (float*)d_out;

  const long long MX = 18464;   // B*N
  const long long MC = 20512;   // B*641

  char* w = (char*)d_ws; size_t off = 0;
  auto alloc = [&](size_t bytes)->void*{ void* p = w + off; off += (bytes + 255) & ~(size_t)255; return p; };

  float* tproj  = (float*)alloc(32*320*4);
  float* hidden = (float*)alloc(32*1280*4);
  float* temb   = (float*)alloc(32*1280*4);
  float* silu_t = (float*)alloc(32*1280*4);
  float* ada    = (float*)alloc(4*32*5120*4);
  u16*  h    = (u16*)alloc(MX*1280*2);
  u16*  cat  = (u16*)alloc(MC*1280*2);
  u16*  lm   = (u16*)alloc(2048*1280*2);
  u16*  lm2  = (u16*)alloc(2048*1280*2);
  u16*  qb   = (u16*)alloc(2048*1280*2);
  u16*  att  = (u16*)alloc(2048*1280*2);
  float* lat = (float*)alloc(2048*1280*4);
  u16*  kvb  = (u16*)alloc(MC*2560*2);
  u16*  Vt   = (u16*)alloc((long long)640*64*672*2);
  u16*  WT_pi  = (u16*)alloc(1280*1152*2);
  u16*  WT_po  = (u16*)alloc((long long)2432*1280*2);
  u16*  WqT    = (u16*)alloc(1280*1280*2);
  u16*  WkvT   = (u16*)alloc(2560*1280*2);
  u16*  WoT    = (u16*)alloc(1280*1280*2);
  u16*  Wff1T  = (u16*)alloc((long long)5120*1280*2);
  u16*  Wff2T  = (u16*)alloc((long long)1280*5120*2);
  // overlaid region: x_bf16 -> (scores/P alternating with ffh) -> proj_out pre-LN
  char* R = (char*)alloc((long long)640*64*672*2);
  u16*  xbf    = (u16*)R;
  u16*  scores = (u16*)R;
  u16*  ffh    = (u16*)R;
  float* po    = (float*)R;

  if (off > ws_size) return; // workspace too small -> fail loudly via wrong output

  // time embedding MLP (f32, exact path: t_emb is output 1)
  kw_timeproj<<<dim3(32), dim3(320), 0, stream>>>(timestep, tproj);
  kw_bias_bcast<<<dim3(32,5), dim3(256), 0, stream>>>(te1_b, hidden, 1280);
  kw_mlp2<<<dim3(5,4), dim3(256), 0, stream>>>(tproj, te1_W, hidden, 320, 1280, 80);
  kw_silu_ip<<<dim3(160), dim3(256), 0, stream>>>(hidden, 32*1280);
  kw_bias_bcast<<<dim3(32,5), dim3(256), 0, stream>>>(te2_b, temb, 1280);
  kw_mlp2<<<dim3(5,8), dim3(256), 0, stream>>>(hidden, te2_W, temb, 1280, 1280, 160);
  kw_post_temb<<<dim3(160), dim3(256), 0, stream>>>(temb, silu_t, out + (long long)2048*2432, 32*1280);

  // adaLN embeddings for all 4 blocks
  kw_ada_init<<<dim3(2560), dim3(256), 0, stream>>>(ada_b, ada);
  kw_ada<<<dim3(20,4,8), dim3(256), 0, stream>>>(silu_t, ada_W, ada);

  // proj_in
  kw_cvt<<<dim3((unsigned)((MX*1152/4 + 255)/256)), dim3(256), 0, stream>>>(x, xbf, MX*1152/4);
  kw_transpose<<<dim3(18,20), dim3(256), 0, stream>>>(proj_in_W, WT_pi, 1152, 1280);
  launch_gemm(stream, xbf, WT_pi, h, (int)MX, 1280, 1280, 1152, 1152, 1152, 1280,
              1, 1, 0,0,0,0,0,0, 1|2|16, proj_in_b, temb, 577);

  kw_init_lat<<<dim3(2048), dim3(256), 0, stream>>>(latents0, lat);
  kw_transpose<<<dim3(20,38), dim3(256), 0, stream>>>(proj_out_W, WT_po, 1280, 2432);

  for (int i = 0; i < 4; i++){
    kw_transpose<<<dim3(20,20), dim3(256), 0, stream>>>(Wq   + (long long)i*1280*1280, WqT,   1280, 1280);
    kw_transpose<<<dim3(20,40), dim3(256), 0, stream>>>(Wkv  + (long long)i*1280*2560, WkvT,  1280, 2560);
    kw_transpose<<<dim3(20,20), dim3(256), 0, stream>>>(Wo   + (long long)i*1280*1280, WoT,   1280, 1280);
    kw_transpose<<<dim3(20,80), dim3(256), 0, stream>>>(Wff1 + (long long)i*1280*5120, Wff1T, 1280, 5120);
    kw_transpose<<<dim3(80,20), dim3(256), 0, stream>>>(Wff2 + (long long)i*5120*1280, Wff2T, 5120, 1280);

    kw_ln_x<<<dim3((unsigned)MX), dim3(256), 0, stream>>>(h, cat, ln0_g + i*1280, ln0_b + i*1280);
    kw_ln_mod<<<dim3(2048), dim3(256), 0, stream>>>(lat, lm, cat, ln1_g + i*1280, ln1_b + i*1280,
                                                    ada + (long long)i*32*5120 + 0);
    // q / kv projections
    launch_gemm(stream, lm,  WqT,  qb,  2048, 1280, 1280, 1280, 1280, 1280, 1280, 1, 1, 0,0,0,0,0,0, 16);
    launch_gemm(stream, cat, WkvT, kvb, (int)MC, 2560, 2560, 1280, 1280, 1280, 2560, 1, 1, 0,0,0,0,0,0, 16);
    // attention: scores = (Q Kt)/8, softmax, att = P V
    launch_gemm(stream, qb, kvb, scores, 64, 641, 672, 64, 1280, 2560, 672,
                640, 20, 81920, 64, 1640960, 64, 860160, 43008, 16);
    kw_softmax<<<dim3(40960), dim3(256), 0, stream>>>(scores);
    kw_vt<<<dim3(640,11), dim3(256), 0, stream>>>(kvb, Vt);
    launch_gemm(stream, scores, Vt, att, 64, 64, 64, 672, 672, 672, 1280,
                640, 20, 860160, 43008, 860160, 43008, 81920, 64, 16);
    // out projection + residual (in-place on lat)
    launch_gemm(stream, att, WoT, lat, 2048, 1280, 1280, 1280, 1280, 1280, 1280,
                1, 1, 0,0,0,0,0,0, 4, nullptr, nullptr, 1, lat, 1280);
    // MLP
    kw_ln_mod<<<dim3(2048), dim3(256), 0, stream>>>(lat, lm2, nullptr, lnada_g + i*1280, lnada_b + i*1280,
                                                    ada + (long long)i*32*5120 + 2560);
    launch_gemm(stream, lm2, Wff1T, ffh, 2048, 5120, 5120, 1280, 1280, 1280, 5120,
                1, 1, 0,0,0,0,0,0, 8|16);
    launch_gemm(stream, ffh, Wff2T, lat, 2048, 1280, 1280, 5120, 5120, 5120, 1280,
                1, 1, 0,0,0,0,0,0, 4, nullptr, nullptr, 1, lat, 1280);
  }

  // proj_out + final LN
  kw_cvt<<<dim3(2560), dim3(256), 0, stream>>>(lat, lm, 2048*1280/4);
  launch_gemm(stream, lm, WT_po, po, 2048, 2432, 2432, 1280, 1280, 1280, 2432,
              1, 1, 0,0,0,0,0,0, 1, proj_out_b);
  kw_ln_out<<<dim3(2048), dim3(256), 0, stream>>>(po, out, norm_out_g, norm_out_b);
}

// Round 3
// 3876.319 us; speedup vs baseline: 1.1568x; 1.0280x over previous
//
#include <hip/hip_runtime.h>
#include <cstdint>
#include <cstddef>

typedef unsigned short u16;
typedef unsigned int u32;
typedef __bf16 bf16x8 __attribute__((ext_vector_type(8)));
typedef float f32x4 __attribute__((ext_vector_type(4)));

__device__ inline float bf2f(u16 h){ union{u32 u; float f;} v; v.u = ((u32)h)<<16; return v.f; }
__device__ inline u16 f2bf(float f){ union{float f; u32 u;} v; v.f=f; u32 r = v.u + 0x7fffu + ((v.u>>16)&1u); return (u16)(r>>16); }

union V16 { uint4 u; bf16x8 b; };

// direct global->LDS, 16B per lane; LDS dest = wave-uniform base + lane*16
__device__ inline void gll16(const u16* g, u16* l){
  __builtin_amdgcn_global_load_lds(
      (const __attribute__((address_space(1))) u32*)g,
      (__attribute__((address_space(3))) u32*)l,
      16, 0, 0);
}

// ---------------- block reduction helpers ----------------
__device__ inline float2 block_red_sum2(float a, float b){
  #pragma unroll
  for (int o=32;o;o>>=1){ a += __shfl_xor(a,o,64); b += __shfl_xor(b,o,64); }
  __shared__ float ta[4], tb[4];
  int w = threadIdx.x>>6;
  if ((threadIdx.x&63)==0){ ta[w]=a; tb[w]=b; }
  __syncthreads();
  float ra = ta[0]+ta[1]+ta[2]+ta[3];
  float rb = tb[0]+tb[1]+tb[2]+tb[3];
  __syncthreads();
  return make_float2(ra, rb);
}
__device__ inline float block_red_max(float a){
  #pragma unroll
  for (int o=32;o;o>>=1) a = fmaxf(a, __shfl_xor(a,o,64));
  __shared__ float tm[4];
  int w = threadIdx.x>>6;
  if ((threadIdx.x&63)==0) tm[w]=a;
  __syncthreads();
  float r = fmaxf(fmaxf(tm[0],tm[1]),fmaxf(tm[2],tm[3]));
  __syncthreads();
  return r;
}
__device__ inline float block_red_sum(float a){
  #pragma unroll
  for (int o=32;o;o>>=1) a += __shfl_xor(a,o,64);
  __shared__ float ts[4];
  int w = threadIdx.x>>6;
  if ((threadIdx.x&63)==0) ts[w]=a;
  __syncthreads();
  float r = ts[0]+ts[1]+ts[2]+ts[3];
  __syncthreads();
  return r;
}

// ---------------- MFMA GEMM: C = A[M,K](bf16) @ Bt[N,K](bf16)^T + epilogue ----------------
// 128x128 tile, BK=32, 256 threads = 4 waves (2x2 of 64x64, each 4x4 of 16x16x32 MFMA).
// global_load_lds width-16 staging with XOR bank swizzle:
//   LDS unit (row, kseg8) stored at block(row/16)*512 + (row%16)*32 + (kseg ^ ((row>>1)&3))*8
//   -> fragment ds_read_b128 hits all 8 16B bank positions across 8 lanes (conflict-free).
// Grid: x = N-tiles (fast) so consecutive blocks share the A tile, stream B.
// flags: 1=+bias[col], 2=+temb[(row/rowdiv)*1280+col], 4=+res[row*ldres+col] (f32), 8=gelu, 16=bf16 out
__global__ __launch_bounds__(256) void kw_gemm(
    const u16* __restrict__ A, const u16* __restrict__ B, void* __restrict__ C,
    int M, int Nclamp, int Nout, int K, int lda, int ldb, int ldc,
    long long sA1, long long sA2, long long sB1, long long sB2, long long sC1, long long sC2,
    int zdiv, int flags,
    const float* __restrict__ bias, const float* __restrict__ temb, int rowdiv,
    const float* __restrict__ res, int ldres)
{
  int z = blockIdx.z;
  int z1 = z / zdiv, z2 = z - z1*zdiv;
  A += z1*sA1 + z2*sA2;
  B += z1*sB1 + z2*sB2;
  long long coff = z1*sC1 + z2*sC2;

  __shared__ u16 As[128*32];
  __shared__ u16 Bs[128*32];

  int tid  = threadIdx.x;
  int lane = tid & 63, wave = tid >> 6;
  int wm = (wave >> 1) * 64, wn = (wave & 1) * 64;
  int lr = lane & 15, quad = lane >> 4;

  int rowBase = blockIdx.y * 128;
  int colBase = blockIdx.x * 128;

  // staging map: wave w, lane l -> row w*16 + l/4, global k-seg ((l&3)^((l>>3)&3))
  int srow = wave*16 + (lane >> 2);
  int sseg = ((lane & 3) ^ ((lane >> 3) & 3)) * 8;

  int ar0 = min(rowBase + srow, M-1);
  int ar1 = min(rowBase + 64 + srow, M-1);
  int br0 = min(colBase + srow, Nclamp-1);
  int br1 = min(colBase + 64 + srow, Nclamp-1);
  const u16* ap0 = A + (long long)ar0*lda + sseg;
  const u16* ap1 = A + (long long)ar1*lda + sseg;
  const u16* bp0 = B + (long long)br0*ldb + sseg;
  const u16* bp1 = B + (long long)br1*ldb + sseg;

  u16* lA0 = As + wave*512;          // rows wave*16 .. +15
  u16* lA1 = As + 2048 + wave*512;   // rows 64+wave*16 .. +15
  u16* lB0 = Bs + wave*512;
  u16* lB1 = Bs + 2048 + wave*512;

  // fragment read offsets (swizzled)
  int swz = (lr >> 1) & 3;
  int rdA = lr*32 + ((quad ^ swz) * 8);   // + block(row/16)*512

  f32x4 acc[4][4];
  #pragma unroll
  for (int mi=0; mi<4; mi++)
    #pragma unroll
    for (int ni=0; ni<4; ni++) acc[mi][ni] = (f32x4){0.f,0.f,0.f,0.f};

  int wmb = wm >> 4;  // block index base for A frags
  int wnb = wn >> 4;

  for (int k0 = 0; k0 < K; k0 += 32) {
    gll16(ap0, lA0);
    gll16(ap1, lA1);
    gll16(bp0, lB0);
    gll16(bp1, lB1);
    __syncthreads();   // vmcnt drain + visibility

    V16 af[4], bf[4];
    #pragma unroll
    for (int mi=0; mi<4; mi++) af[mi].u = *(const uint4*)&As[(wmb + mi)*512 + rdA];
    #pragma unroll
    for (int ni=0; ni<4; ni++) bf[ni].u = *(const uint4*)&Bs[(wnb + ni)*512 + rdA];
    #pragma unroll
    for (int mi=0; mi<4; mi++)
      #pragma unroll
      for (int ni=0; ni<4; ni++)
        acc[mi][ni] = __builtin_amdgcn_mfma_f32_16x16x32_bf16(af[mi].b, bf[ni].b, acc[mi][ni], 0, 0, 0);

    __syncthreads();   // all reads done before next overwrite
    ap0 += 32; ap1 += 32; bp0 += 32; bp1 += 32;
  }

  // epilogue
  #pragma unroll
  for (int mi=0; mi<4; mi++){
    #pragma unroll
    for (int ni=0; ni<4; ni++){
      #pragma unroll
      for (int rr=0; rr<4; rr++){
        int row = rowBase + wm + mi*16 + quad*4 + rr;
        int col = colBase + wn + ni*16 + lr;
        if (row < M && col < Nout){
          float x = acc[mi][ni][rr];
          if (flags & 1) x += bias[col];
          if (flags & 2) x += temb[(long long)(row/rowdiv)*1280 + col];
          if (flags & 4) x += res[(long long)row*ldres + col];
          if (flags & 8) x = 0.5f*x*(1.f + erff(x*0.70710678118654752f));
          long long o = coff + (long long)row*ldc + col;
          if (flags & 16) ((u16*)C)[o] = f2bf(x);
          else            ((float*)C)[o] = x;
        }
      }
    }
  }
}

// ---------------- transpose f32[K,N] -> bf16[N,K] ----------------
__global__ __launch_bounds__(256) void kw_transpose(const float* __restrict__ in, u16* __restrict__ out,
                                                    int K, int N)
{
  __shared__ u16 t[64][68];
  int k0 = blockIdx.x*64, n0 = blockIdx.y*64;
  int tid = threadIdx.x; int c = tid & 63; int r4 = tid >> 6;
  #pragma unroll
  for (int p = 0; p < 16; p++){
    int kr = r4 + p*4;
    t[kr][c] = f2bf(in[(long long)(k0+kr)*N + n0 + c]);
  }
  __syncthreads();
  #pragma unroll
  for (int p = 0; p < 16; p++){
    int nr = r4 + p*4;
    out[(long long)(n0+nr)*K + k0 + c] = t[c][nr];
  }
}

// ---------------- V transpose: kv[b,key,1280+h*64+d] -> Vt[bh, d, keypad672] ----------------
__global__ __launch_bounds__(256) void kw_vt(const u16* __restrict__ kv, u16* __restrict__ Vt)
{
  int z = blockIdx.x; int kt = blockIdx.y;
  int b = z / 20, hh = z - b*20;
  const u16* src = kv + (long long)b*641*2560 + 1280 + hh*64;
  u16* dst = Vt + (long long)z*64*672;
  __shared__ u16 t[64][68];
  int tid = threadIdx.x; int c = tid & 63; int r4 = tid >> 6;
  #pragma unroll
  for (int p = 0; p < 16; p++){
    int krow = r4 + p*4;
    int key = kt*64 + krow;
    t[krow][c] = (key < 641) ? src[(long long)key*2560 + c] : (u16)0;
  }
  __syncthreads();
  #pragma unroll
  for (int p = 0; p < 16; p++){
    int d = r4 + p*4;
    int key = kt*64 + c;
    if (key < 672) dst[(long long)d*672 + key] = t[c][d];
  }
}

// ---------------- softmax in-place over bf16 scores rows of 672 (valid 641), scale 1/8 ----------------
__global__ __launch_bounds__(256) void kw_softmax(u16* __restrict__ sc)
{
  u16* row = sc + (long long)blockIdx.x * 672;
  int tid = threadIdx.x;
  float v[3];
  float mx = -1e30f;
  #pragma unroll
  for (int i=0;i<3;i++){
    int c = tid + i*256;
    if (c < 641){ v[i] = bf2f(row[c])*0.125f; mx = fmaxf(mx, v[i]); } else v[i] = -1e30f;
  }
  float M = block_red_max(mx);
  float s = 0.f;
  #pragma unroll
  for (int i=0;i<3;i++){
    int c = tid + i*256;
    if (c < 641){ v[i] = __expf(v[i]-M); s += v[i]; }
  }
  float S = block_red_sum(s);
  float inv = 1.0f / S;
  #pragma unroll
  for (int i=0;i<3;i++){
    int c = tid + i*256;
    if (c < 672) row[c] = (c < 641) ? f2bf(v[i]*inv) : (u16)0;
  }
}

// ---------------- time embedding ----------------
__global__ void kw_timeproj(const float* __restrict__ tstep, float* __restrict__ tproj)
{
  int b = blockIdx.x; int j = threadIdx.x; // 320
  float t = tstep[b];
  int idx = (j < 160) ? j : (j - 160);
  float freq = expf(-9.210340371976184f * (float)idx / 160.0f);
  float a = t * freq;
  tproj[b*320 + j] = (j < 160) ? cosf(a) : sinf(a);
}

// broadcast bias into out[32,N]
__global__ void kw_bias_bcast(const float* __restrict__ bias, float* __restrict__ out, int N)
{
  int b = blockIdx.x; int n = blockIdx.y*256 + threadIdx.x;
  if (n < N) out[(long long)b*N + n] = bias[n];
}

// dense layer, W-read-once k-split: out[b,n] += sum_k in[b,k0+k] * W[k0+k, n]  (atomic)
__global__ __launch_bounds__(256) void kw_mlp2(const float* __restrict__ in, const float* __restrict__ W,
    float* __restrict__ out, int K, int N, int kc)
{
  int n = blockIdx.x*256 + threadIdx.x;
  int k0 = blockIdx.y * kc;
  __shared__ float sbuf[32*160];
  for (int idx = threadIdx.x; idx < 32*kc; idx += 256){
    int b = idx / kc, k = idx - b*kc;
    sbuf[idx] = in[(long long)b*K + k0 + k];
  }
  __syncthreads();
  float acc[32];
  #pragma unroll
  for (int b=0;b<32;b++) acc[b]=0.f;
  const float* wp = W + (long long)k0*N + n;
  for (int k=0;k<kc;k++){
    float wv = wp[(long long)k*N];
    #pragma unroll
    for (int b=0;b<32;b++) acc[b] = fmaf(sbuf[b*kc+k], wv, acc[b]);
  }
  #pragma unroll
  for (int b=0;b<32;b++) atomicAdd(out + (long long)b*N + n, acc[b]);
}

__global__ void kw_silu_ip(float* __restrict__ p, int n)
{
  int i = blockIdx.x*256 + threadIdx.x;
  if (i < n){ float x = p[i]; p[i] = x/(1.f+expf(-x)); }
}

// silu_t = silu(temb); copy temb -> t_emb output
__global__ void kw_post_temb(const float* __restrict__ temb, float* __restrict__ silu_t,
                             float* __restrict__ tout, int n)
{
  int i = blockIdx.x*256 + threadIdx.x;
  if (i < n){
    float x = temb[i];
    silu_t[i] = x/(1.f+expf(-x));
    tout[i] = x;
  }
}

__global__ void kw_ada_init(const float* __restrict__ ada_b, float* __restrict__ ada)
{
  int idx = blockIdx.x*256 + threadIdx.x;
  if (idx < 4*32*5120){
    int i = idx / (32*5120);
    int j = idx % 5120;
    ada[idx] = ada_b[i*5120 + j];
  }
}

__global__ __launch_bounds__(256) void kw_ada(const float* __restrict__ silu_t,
    const float* __restrict__ adaW, float* __restrict__ ada)
{
  int jt = blockIdx.x, i = blockIdx.y, ks = blockIdx.z;
  int tid = threadIdx.x;
  int j = jt*256 + tid;
  __shared__ float sbuf[32][160];
  #pragma unroll
  for (int p = 0; p < 20; p++){
    int idx = tid + p*256;
    int b = idx / 160, k = idx - b*160;
    sbuf[b][k] = silu_t[b*1280 + ks*160 + k];
  }
  __syncthreads();
  float acc[32];
  #pragma unroll
  for (int b=0;b<32;b++) acc[b]=0.f;
  const float* wp = adaW + ((long long)i*1280 + ks*160)*5120 + j;
  for (int k=0;k<160;k++){
    float w = wp[(long long)k*5120];
    #pragma unroll
    for (int b=0;b<32;b++) acc[b] = fmaf(sbuf[b][k], w, acc[b]);
  }
  float* op = ada + (long long)i*32*5120 + j;
  for (int b=0;b<32;b++) atomicAdd(op + (long long)b*5120, acc[b]);
}

__global__ void kw_init_lat(const float* __restrict__ l0, float* __restrict__ lat)
{
  int r = blockIdx.x; int q = r & 63;
  #pragma unroll
  for (int i=0;i<5;i++){
    int c = threadIdx.x + i*256;
    lat[(long long)r*1280 + c] = l0[q*1280 + c];
  }
}

__global__ void kw_cvt(const float* __restrict__ in, u16* __restrict__ out, long long n4)
{
  long long i = ((long long)blockIdx.x*256 + threadIdx.x);
  if (i < n4){
    float4 v = *(const float4*)(in + i*4);
    u32 lo = (u32)f2bf(v.x) | ((u32)f2bf(v.y)<<16);
    u32 hi = (u32)f2bf(v.z) | ((u32)f2bf(v.w)<<16);
    uint2 o; o.x = lo; o.y = hi;
    *(uint2*)(out + i*4) = o;
  }
}

// LN over H=1280, bf16 in -> bf16 out into cat[b*641 + (r%577)]
__global__ __launch_bounds__(256) void kw_ln_x(const u16* __restrict__ h, u16* __restrict__ cat,
    const float* __restrict__ g, const float* __restrict__ bb)
{
  int r = blockIdx.x;
  int batch = r / 577; int rr = r - batch*577;
  const u16* row = h + (long long)r*1280;
  u16* orow = cat + ((long long)batch*641 + rr)*1280;
  int tid = threadIdx.x;
  float v[5]; float s=0.f, s2=0.f;
  #pragma unroll
  for (int i=0;i<5;i++){ float x = bf2f(row[tid+i*256]); v[i]=x; s+=x; s2+=x*x; }
  float2 r2 = block_red_sum2(s, s2);
  float mean = r2.x * (1.f/1280.f);
  float var  = r2.y * (1.f/1280.f) - mean*mean;
  float rstd = rsqrtf(var + 1e-5f);
  #pragma unroll
  for (int i=0;i<5;i++){
    int c = tid+i*256;
    orow[c] = f2bf((v[i]-mean)*rstd*g[c] + bb[c]);
  }
}

// LN over H=1280, f32 in, * (1+sc)+sh, bf16 out (+ optional copy into cat at row b*641+577+q)
__global__ __launch_bounds__(256) void kw_ln_mod(const float* __restrict__ lat, u16* __restrict__ out1,
    u16* __restrict__ cat, const float* __restrict__ g, const float* __restrict__ bb,
    const float* __restrict__ adabase)
{
  int r = blockIdx.x;
  int b = r >> 6, q = r & 63;
  const float* row = lat + (long long)r*1280;
  const float* ab = adabase + (long long)b*5120;
  int tid = threadIdx.x;
  float v[5]; float s=0.f, s2=0.f;
  #pragma unroll
  for (int i=0;i<5;i++){ float x = row[tid+i*256]; v[i]=x; s+=x; s2+=x*x; }
  float2 r2 = block_red_sum2(s, s2);
  float mean = r2.x * (1.f/1280.f);
  float var  = r2.y * (1.f/1280.f) - mean*mean;
  float rstd = rsqrtf(var + 1e-5f);
  #pragma unroll
  for (int i=0;i<5;i++){
    int c = tid+i*256;
    float sh = ab[c], sc = ab[1280+c];
    float y = ((v[i]-mean)*rstd*g[c] + bb[c])*(1.f+sc) + sh;
    u16 o = f2bf(y);
    out1[(long long)r*1280 + c] = o;
    if (cat) cat[((long long)b*641 + 577 + q)*1280 + c] = o;
  }
}

// final LN over O=2432, f32 in -> f32 out
__global__ __launch_bounds__(256) void kw_ln_out(const float* __restrict__ in, float* __restrict__ out,
    const float* __restrict__ g, const float* __restrict__ bb)
{
  int r = blockIdx.x;
  const float* row = in + (long long)r*2432;
  int tid = threadIdx.x;
  float v[10]; float s=0.f, s2=0.f;
  #pragma unroll
  for (int i=0;i<10;i++){
    int c = tid + i*256;
    float x = (c < 2432) ? row[c] : 0.f;
    v[i]=x; s+=x; s2+=x*x;
  }
  float2 r2 = block_red_sum2(s, s2);
  float mean = r2.x * (1.f/2432.f);
  float var  = r2.y * (1.f/2432.f) - mean*mean;
  float rstd = rsqrtf(var + 1e-5f);
  #pragma unroll
  for (int i=0;i<10;i++){
    int c = tid + i*256;
    if (c < 2432) out[(long long)r*2432 + c] = (v[i]-mean)*rstd*g[c] + bb[c];
  }
}

// ---------------- host ----------------
static inline void launch_gemm(hipStream_t s, const u16* A, const u16* B, void* C,
    int M, int Nclamp, int Nout, int K, int lda, int ldb, int ldc,
    int nz, int zdiv, long long sA1, long long sA2, long long sB1, long long sB2,
    long long sC1, long long sC2, int flags,
    const float* bias = nullptr, const float* temb = nullptr, int rowdiv = 1,
    const float* res = nullptr, int ldres = 0)
{
  dim3 g((Nout+127)/128, (M+127)/128, nz);   // x = N-tiles (fast): blocks share A tile, stream B
  kw_gemm<<<g, dim3(256), 0, s>>>(A,B,C,M,Nclamp,Nout,K,lda,ldb,ldc,
      sA1,sA2,sB1,sB2,sC1,sC2,zdiv,flags,bias,temb,rowdiv,res,ldres);
}

extern "C" void kernel_launch(void* const* d_in, const int* in_sizes, int n_in,
                              void* d_out, int out_size, void* d_ws, size_t ws_size,
                              hipStream_t stream)
{
  const float* x         = (const float*)d_in[0];
  const float* timestep  = (const float*)d_in[1];
  const float* latents0  = (const float*)d_in[2];
  const float* proj_in_W = (const float*)d_in[3];
  const float* proj_in_b = (const float*)d_in[4];
  const float* te1_W     = (const float*)d_in[5];
  const float* te1_b     = (const float*)d_in[6];
  const float* te2_W     = (const float*)d_in[7];
  const float* te2_b     = (const float*)d_in[8];
  const float* ln0_g     = (const float*)d_in[9];
  const float* ln0_b     = (const float*)d_in[10];
  const float* ln1_g     = (const float*)d_in[11];
  const float* ln1_b     = (const float*)d_in[12];
  const float* Wq        = (const float*)d_in[13];
  const float* Wkv       = (const float*)d_in[14];
  const float* Wo        = (const float*)d_in[15];
  const float* ada_W     = (const float*)d_in[16];
  const float* ada_b     = (const float*)d_in[17];
  const float* lnada_g   = (const float*)d_in[18];
  const float* lnada_b   = (const float*)d_in[19];
  const float* Wff1      = (const float*)d_in[20];
  const float* Wff2      = (const float*)d_in[21];
  const float* proj_out_W= (const float*)d_in[22];
  const float* proj_out_b= (const float*)d_in[23];
  const float* norm_out_g= (const float*)d_in[24];
  const float* norm_out_b= (const float*)d_in[25];
  float* out = (float*)d_out;

  const long long MX = 18464;   // B*N
  const long long MC = 20512;   // B*641

  char* w = (char*)d_ws; size_t off = 0;
  auto alloc = [&](size_t bytes)->void*{ void* p = w + off; off += (bytes + 255) & ~(size_t)255; return p; };

  float* tproj  = (float*)alloc(32*320*4);
  float* hidden = (float*)alloc(32*1280*4);
  float* temb   = (float*)alloc(32*1280*4);
  float* silu_t = (float*)alloc(32*1280*4);
  float* ada    = (float*)alloc(4*32*5120*4);
  u16*  h    = (u16*)alloc(MX*1280*2);
  u16*  cat  = (u16*)alloc(MC*1280*2);
  u16*  lm   = (u16*)alloc(2048*1280*2);
  u16*  lm2  = (u16*)alloc(2048*1280*2);
  u16*  qb   = (u16*)alloc(2048*1280*2);
  u16*  att  = (u16*)alloc(2048*1280*2);
  float* lat = (float*)alloc(2048*1280*4);
  u16*  kvb  = (u16*)alloc(MC*2560*2);
  u16*  Vt   = (u16*)alloc((long long)640*64*672*2);
  u16*  WT_pi  = (u16*)alloc(1280*1152*2);
  u16*  WT_po  = (u16*)alloc((long long)2432*1280*2);
  u16*  WqT    = (u16*)alloc(1280*1280*2);
  u16*  WkvT   = (u16*)alloc(2560*1280*2);
  u16*  WoT    = (u16*)alloc(1280*1280*2);
  u16*  Wff1T  = (u16*)alloc((long long)5120*1280*2);
  u16*  Wff2T  = (u16*)alloc((long long)1280*5120*2);
  // overlaid region: x_bf16 -> (scores/P alternating with ffh) -> proj_out pre-LN
  char* R = (char*)alloc((long long)640*64*672*2);
  u16*  xbf    = (u16*)R;
  u16*  scores = (u16*)R;
  u16*  ffh    = (u16*)R;
  float* po    = (float*)R;

  if (off > ws_size) return; // workspace too small -> fail loudly via wrong output

  // time embedding MLP (f32, exact path: t_emb is output 1)
  kw_timeproj<<<dim3(32), dim3(320), 0, stream>>>(timestep, tproj);
  kw_bias_bcast<<<dim3(32,5), dim3(256), 0, stream>>>(te1_b, hidden, 1280);
  kw_mlp2<<<dim3(5,4), dim3(256), 0, stream>>>(tproj, te1_W, hidden, 320, 1280, 80);
  kw_silu_ip<<<dim3(160), dim3(256), 0, stream>>>(hidden, 32*1280);
  kw_bias_bcast<<<dim3(32,5), dim3(256), 0, stream>>>(te2_b, temb, 1280);
  kw_mlp2<<<dim3(5,8), dim3(256), 0, stream>>>(hidden, te2_W, temb, 1280, 1280, 160);
  kw_post_temb<<<dim3(160), dim3(256), 0, stream>>>(temb, silu_t, out + (long long)2048*2432, 32*1280);

  // adaLN embeddings for all 4 blocks
  kw_ada_init<<<dim3(2560), dim3(256), 0, stream>>>(ada_b, ada);
  kw_ada<<<dim3(20,4,8), dim3(256), 0, stream>>>(silu_t, ada_W, ada);

  // proj_in
  kw_cvt<<<dim3((unsigned)((MX*1152/4 + 255)/256)), dim3(256), 0, stream>>>(x, xbf, MX*1152/4);
  kw_transpose<<<dim3(18,20), dim3(256), 0, stream>>>(proj_in_W, WT_pi, 1152, 1280);
  launch_gemm(stream, xbf, WT_pi, h, (int)MX, 1280, 1280, 1152, 1152, 1152, 1280,
              1, 1, 0,0,0,0,0,0, 1|2|16, proj_in_b, temb, 577);

  kw_init_lat<<<dim3(2048), dim3(256), 0, stream>>>(latents0, lat);
  kw_transpose<<<dim3(20,38), dim3(256), 0, stream>>>(proj_out_W, WT_po, 1280, 2432);

  for (int i = 0; i < 4; i++){
    kw_transpose<<<dim3(20,20), dim3(256), 0, stream>>>(Wq   + (long long)i*1280*1280, WqT,   1280, 1280);
    kw_transpose<<<dim3(20,40), dim3(256), 0, stream>>>(Wkv  + (long long)i*1280*2560, WkvT,  1280, 2560);
    kw_transpose<<<dim3(20,20), dim3(256), 0, stream>>>(Wo   + (long long)i*1280*1280, WoT,   1280, 1280);
    kw_transpose<<<dim3(20,80), dim3(256), 0, stream>>>(Wff1 + (long long)i*1280*5120, Wff1T, 1280, 5120);
    kw_transpose<<<dim3(80,20), dim3(256), 0, stream>>>(Wff2 + (long long)i*5120*1280, Wff2T, 5120, 1280);

    kw_ln_x<<<dim3((unsigned)MX), dim3(256), 0, stream>>>(h, cat, ln0_g + i*1280, ln0_b + i*1280);
    kw_ln_mod<<<dim3(2048), dim3(256), 0, stream>>>(lat, lm, cat, ln1_g + i*1280, ln1_b + i*1280,
                                                    ada + (long long)i*32*5120 + 0);
    // q / kv projections
    launch_gemm(stream, lm,  WqT,  qb,  2048, 1280, 1280, 1280, 1280, 1280, 1280, 1, 1, 0,0,0,0,0,0, 16);
    launch_gemm(stream, cat, WkvT, kvb, (int)MC, 2560, 2560, 1280, 1280, 1280, 2560, 1, 1, 0,0,0,0,0,0, 16);
    // attention: scores = (Q Kt)/8, softmax, att = P V
    launch_gemm(stream, qb, kvb, scores, 64, 641, 672, 64, 1280, 2560, 672,
                640, 20, 81920, 64, 1640960, 64, 860160, 43008, 16);
    kw_softmax<<<dim3(40960), dim3(256), 0, stream>>>(scores);
    kw_vt<<<dim3(640,11), dim3(256), 0, stream>>>(kvb, Vt);
    launch_gemm(stream, scores, Vt, att, 64, 64, 64, 672, 672, 672, 1280,
                640, 20, 860160, 43008, 860160, 43008, 81920, 64, 16);
    // out projection + residual (in-place on lat)
    launch_gemm(stream, att, WoT, lat, 2048, 1280, 1280, 1280, 1280, 1280, 1280,
                1, 1, 0,0,0,0,0,0, 4, nullptr, nullptr, 1, lat, 1280);
    // MLP
    kw_ln_mod<<<dim3(2048), dim3(256), 0, stream>>>(lat, lm2, nullptr, lnada_g + i*1280, lnada_b + i*1280,
                                                    ada + (long long)i*32*5120 + 2560);
    launch_gemm(stream, lm2, Wff1T, ffh, 2048, 5120, 5120, 1280, 1280, 1280, 5120,
                1, 1, 0,0,0,0,0,0, 8|16);
    launch_gemm(stream, ffh, Wff2T, lat, 2048, 1280, 1280, 5120, 5120, 5120, 1280,
                1, 1, 0,0,0,0,0,0, 4, nullptr, nullptr, 1, lat, 1280);
  }

  // proj_out + final LN
  kw_cvt<<<dim3(2560), dim3(256), 0, stream>>>(lat, lm, 2048*1280/4);
  launch_gemm(stream, lm, WT_po, po, 2048, 2432, 2432, 1280, 1280, 1280, 2432,
              1, 1, 0,0,0,0,0,0, 1, proj_out_b);
  kw_ln_out<<<dim3(2048), dim3(256), 0, stream>>>(po, out, norm_out_g, norm_out_b);
}

// Round 4
// 3611.223 us; speedup vs baseline: 1.2417x; 1.0734x over previous
//
#include <hip/hip_runtime.h>
#include <cstdint>
#include <cstddef>

typedef unsigned short u16;
typedef unsigned int u32;
typedef __bf16 bf16x8 __attribute__((ext_vector_type(8)));
typedef float f32x4 __attribute__((ext_vector_type(4)));

__device__ inline float bf2f(u16 h){ union{u32 u; float f;} v; v.u = ((u32)h)<<16; return v.f; }
__device__ inline u16 f2bf(float f){ union{float f; u32 u;} v; v.f=f; u32 r = v.u + 0x7fffu + ((v.u>>16)&1u); return (u16)(r>>16); }

union V16 { uint4 u; bf16x8 b; };

// direct global->LDS, 16B per lane; LDS dest = wave-uniform base + lane*16
__device__ inline void gll16(const u16* g, u16* l){
  __builtin_amdgcn_global_load_lds(
      (const __attribute__((address_space(1))) u32*)g,
      (__attribute__((address_space(3))) u32*)l,
      16, 0, 0);
}

// ---------------- block reduction helpers ----------------
__device__ inline float2 block_red_sum2(float a, float b){
  #pragma unroll
  for (int o=32;o;o>>=1){ a += __shfl_xor(a,o,64); b += __shfl_xor(b,o,64); }
  __shared__ float ta[4], tb[4];
  int w = threadIdx.x>>6;
  if ((threadIdx.x&63)==0){ ta[w]=a; tb[w]=b; }
  __syncthreads();
  float ra = ta[0]+ta[1]+ta[2]+ta[3];
  float rb = tb[0]+tb[1]+tb[2]+tb[3];
  __syncthreads();
  return make_float2(ra, rb);
}

// ---------------- MFMA GEMM: C = A[M,K](bf16) @ Bt[N,K](bf16)^T + epilogue ----------------
// 128x128 tile, BK=64 (two 32-stages, one barrier pair per 64-K), 256 threads = 4 waves.
// global_load_lds width-16 staging with XOR bank swizzle (conflict-free b128 frag reads).
// Grid: x = N-tiles (fast) so consecutive blocks share the A tile, stream B.
// flags: 1=+bias[col], 2=+temb[(row/rowdiv)*1280+col], 4=+res[row*ldres+col] (f32), 8=gelu, 16=bf16 out
__global__ __launch_bounds__(256) void kw_gemm(
    const u16* __restrict__ A, const u16* __restrict__ B, void* __restrict__ C,
    int M, int Nclamp, int Nout, int K, int lda, int ldb, int ldc,
    long long sA1, long long sA2, long long sB1, long long sB2, long long sC1, long long sC2,
    int zdiv, int flags,
    const float* __restrict__ bias, const float* __restrict__ temb, int rowdiv,
    const float* __restrict__ res, int ldres)
{
  int z = blockIdx.z;
  int z1 = z / zdiv, z2 = z - z1*zdiv;
  A += z1*sA1 + z2*sA2;
  B += z1*sB1 + z2*sB2;
  long long coff = z1*sC1 + z2*sC2;

  __shared__ u16 As[2*128*32];   // two 32-K stages
  __shared__ u16 Bs[2*128*32];

  int tid  = threadIdx.x;
  int lane = tid & 63, wave = tid >> 6;
  int wm = (wave >> 1) * 64, wn = (wave & 1) * 64;
  int lr = lane & 15, quad = lane >> 4;

  int rowBase = blockIdx.y * 128;
  int colBase = blockIdx.x * 128;

  // staging map: wave w, lane l -> row w*16 + l/4, global k-seg ((l&3)^((l>>3)&3))
  int srow = wave*16 + (lane >> 2);
  int sseg = ((lane & 3) ^ ((lane >> 3) & 3)) * 8;

  int ar0 = min(rowBase + srow, M-1);
  int ar1 = min(rowBase + 64 + srow, M-1);
  int br0 = min(colBase + srow, Nclamp-1);
  int br1 = min(colBase + 64 + srow, Nclamp-1);
  const u16* ap0 = A + (long long)ar0*lda + sseg;
  const u16* ap1 = A + (long long)ar1*lda + sseg;
  const u16* bp0 = B + (long long)br0*ldb + sseg;
  const u16* bp1 = B + (long long)br1*ldb + sseg;

  u16* lA0 = As + wave*512;          // rows wave*16 .. +15
  u16* lA1 = As + 2048 + wave*512;   // rows 64+wave*16 .. +15
  u16* lB0 = Bs + wave*512;
  u16* lB1 = Bs + 2048 + wave*512;

  // fragment read offsets (swizzled)
  int swz = (lr >> 1) & 3;
  int rdA = lr*32 + ((quad ^ swz) * 8);   // + block(row/16)*512

  f32x4 acc[4][4];
  #pragma unroll
  for (int mi=0; mi<4; mi++)
    #pragma unroll
    for (int ni=0; ni<4; ni++) acc[mi][ni] = (f32x4){0.f,0.f,0.f,0.f};

  int wmb = wm >> 4;
  int wnb = wn >> 4;

  for (int k0 = 0; k0 < K; k0 += 64) {
    gll16(ap0, lA0);
    gll16(ap1, lA1);
    gll16(bp0, lB0);
    gll16(bp1, lB1);
    gll16(ap0+32, lA0+4096);
    gll16(ap1+32, lA1+4096);
    gll16(bp0+32, lB0+4096);
    gll16(bp1+32, lB1+4096);
    __syncthreads();   // vmcnt drain + visibility

    {
      V16 af[4], bf[4];
      #pragma unroll
      for (int mi=0; mi<4; mi++) af[mi].u = *(const uint4*)&As[(wmb + mi)*512 + rdA];
      #pragma unroll
      for (int ni=0; ni<4; ni++) bf[ni].u = *(const uint4*)&Bs[(wnb + ni)*512 + rdA];
      #pragma unroll
      for (int mi=0; mi<4; mi++)
        #pragma unroll
        for (int ni=0; ni<4; ni++)
          acc[mi][ni] = __builtin_amdgcn_mfma_f32_16x16x32_bf16(af[mi].b, bf[ni].b, acc[mi][ni], 0, 0, 0);
    }
    {
      V16 af[4], bf[4];
      #pragma unroll
      for (int mi=0; mi<4; mi++) af[mi].u = *(const uint4*)&As[4096 + (wmb + mi)*512 + rdA];
      #pragma unroll
      for (int ni=0; ni<4; ni++) bf[ni].u = *(const uint4*)&Bs[4096 + (wnb + ni)*512 + rdA];
      #pragma unroll
      for (int mi=0; mi<4; mi++)
        #pragma unroll
        for (int ni=0; ni<4; ni++)
          acc[mi][ni] = __builtin_amdgcn_mfma_f32_16x16x32_bf16(af[mi].b, bf[ni].b, acc[mi][ni], 0, 0, 0);
    }

    __syncthreads();
    ap0 += 64; ap1 += 64; bp0 += 64; bp1 += 64;
  }

  // epilogue
  #pragma unroll
  for (int mi=0; mi<4; mi++){
    #pragma unroll
    for (int ni=0; ni<4; ni++){
      #pragma unroll
      for (int rr=0; rr<4; rr++){
        int row = rowBase + wm + mi*16 + quad*4 + rr;
        int col = colBase + wn + ni*16 + lr;
        if (row < M && col < Nout){
          float x = acc[mi][ni][rr];
          if (flags & 1) x += bias[col];
          if (flags & 2) x += temb[(long long)(row/rowdiv)*1280 + col];
          if (flags & 4) x += res[(long long)row*ldres + col];
          if (flags & 8) x = 0.5f*x*(1.f + erff(x*0.70710678118654752f));
          long long o = coff + (long long)row*ldc + col;
          if (flags & 16) ((u16*)C)[o] = f2bf(x);
          else            ((float*)C)[o] = x;
        }
      }
    }
  }
}

// ---------------- fused flash attention: one block per (b,h) ----------------
// Q[32][64][1280] (qb), K rows kvb[b][key][h*64+..], Vt[640][64][672] (zero-padded keys>=641)
// out att[32][64][1280]. Online softmax, scale 1/8 on scores.
__global__ __launch_bounds__(256) void kw_flash(
    const u16* __restrict__ qb, const u16* __restrict__ kvb,
    const u16* __restrict__ Vt, u16* __restrict__ att)
{
  int z = blockIdx.x;
  int b = z / 20, h = z - b*20;
  int tid = threadIdx.x, lane = tid & 63, wave = tid >> 6;
  int lr = lane & 15, quad = lane >> 4;

  __shared__ u16 P[4][16][72];   // per-wave P strip (16 q-rows x 64 keys)

  // Q A-frags: m=lr (q row within strip), k=quad*8+j
  const u16* qrow = qb + ((long long)(b*64 + wave*16 + lr))*1280 + h*64;
  V16 aq[2];
  aq[0].u = *(const uint4*)(qrow + quad*8);
  aq[1].u = *(const uint4*)(qrow + 32 + quad*8);

  f32x4 Oacc[4];
  #pragma unroll
  for (int nt=0; nt<4; nt++) Oacc[nt] = (f32x4){0.f,0.f,0.f,0.f};
  float mst[4], lst[4];
  #pragma unroll
  for (int rr=0; rr<4; rr++){ mst[rr] = -3e38f; lst[rr] = 0.f; }

  const u16* kbase = kvb + (long long)b*641*2560 + h*64;
  const u16* vtb   = Vt + (long long)z*64*672;

  for (int kt = 0; kt < 11; kt++){
    int key0 = kt*64;
    // K B-frags: n=key (lr + nt*16), k=d
    V16 bk0[4], bk1[4];
    #pragma unroll
    for (int nt=0; nt<4; nt++){
      int key = min(key0 + nt*16 + lr, 640);
      const u16* kr = kbase + (long long)key*2560;
      bk0[nt].u = *(const uint4*)(kr + quad*8);
      bk1[nt].u = *(const uint4*)(kr + 32 + quad*8);
    }
    f32x4 S[4];
    #pragma unroll
    for (int nt=0; nt<4; nt++){
      S[nt] = (f32x4){0.f,0.f,0.f,0.f};
      S[nt] = __builtin_amdgcn_mfma_f32_16x16x32_bf16(aq[0].b, bk0[nt].b, S[nt], 0,0,0);
      S[nt] = __builtin_amdgcn_mfma_f32_16x16x32_bf16(aq[1].b, bk1[nt].b, S[nt], 0,0,0);
    }
    // scale + mask + row max
    float rm[4];
    #pragma unroll
    for (int rr=0; rr<4; rr++) rm[rr] = -3e38f;
    #pragma unroll
    for (int nt=0; nt<4; nt++){
      bool valid = (key0 + nt*16 + lr) < 641;
      #pragma unroll
      for (int rr=0; rr<4; rr++){
        float v = valid ? S[nt][rr]*0.125f : -3e38f;
        S[nt][rr] = v;
        rm[rr] = fmaxf(rm[rr], v);
      }
    }
    #pragma unroll
    for (int o=1; o<16; o<<=1)
      #pragma unroll
      for (int rr=0; rr<4; rr++) rm[rr] = fmaxf(rm[rr], __shfl_xor(rm[rr], o, 64));
    // online update
    float alpha[4];
    #pragma unroll
    for (int rr=0; rr<4; rr++){
      float mn = fmaxf(mst[rr], rm[rr]);
      alpha[rr] = __expf(mst[rr] - mn);
      mst[rr] = mn;
    }
    float rs[4] = {0.f,0.f,0.f,0.f};
    #pragma unroll
    for (int nt=0; nt<4; nt++)
      #pragma unroll
      for (int rr=0; rr<4; rr++){
        float p = __expf(S[nt][rr] - mst[rr]);
        S[nt][rr] = p;
        rs[rr] += p;
      }
    #pragma unroll
    for (int o=1; o<16; o<<=1)
      #pragma unroll
      for (int rr=0; rr<4; rr++) rs[rr] += __shfl_xor(rs[rr], o, 64);
    #pragma unroll
    for (int rr=0; rr<4; rr++) lst[rr] = lst[rr]*alpha[rr] + rs[rr];
    // P -> LDS (C-layout to A-layout round trip)
    #pragma unroll
    for (int nt=0; nt<4; nt++)
      #pragma unroll
      for (int rr=0; rr<4; rr++)
        P[wave][quad*4+rr][nt*16+lr] = f2bf(S[nt][rr]);
    __syncthreads();
    // scale O
    #pragma unroll
    for (int nt=0; nt<4; nt++)
      #pragma unroll
      for (int rr=0; rr<4; rr++) Oacc[nt][rr] *= alpha[rr];
    // PV
    V16 ap[2];
    ap[0].u = *(const uint4*)&P[wave][lr][quad*8];
    ap[1].u = *(const uint4*)&P[wave][lr][32 + quad*8];
    #pragma unroll
    for (int nt=0; nt<4; nt++){
      const u16* vr = vtb + (long long)(nt*16 + lr)*672 + key0;
      V16 bv0, bv1;
      bv0.u = *(const uint4*)(vr + quad*8);
      bv1.u = *(const uint4*)(vr + 32 + quad*8);
      Oacc[nt] = __builtin_amdgcn_mfma_f32_16x16x32_bf16(ap[0].b, bv0.b, Oacc[nt], 0,0,0);
      Oacc[nt] = __builtin_amdgcn_mfma_f32_16x16x32_bf16(ap[1].b, bv1.b, Oacc[nt], 0,0,0);
    }
    __syncthreads();
  }
  // epilogue: att[b*64 + wave*16 + quad*4+rr][h*64 + nt*16+lr] = O/l
  float inv[4];
  #pragma unroll
  for (int rr=0; rr<4; rr++) inv[rr] = 1.0f / lst[rr];
  #pragma unroll
  for (int nt=0; nt<4; nt++)
    #pragma unroll
    for (int rr=0; rr<4; rr++){
      long long row = b*64 + wave*16 + quad*4 + rr;
      att[row*1280 + h*64 + nt*16 + lr] = f2bf(Oacc[nt][rr]*inv[rr]);
    }
}

// ---------------- transpose f32[K,N] -> bf16[N,K] ----------------
__global__ __launch_bounds__(256) void kw_transpose(const float* __restrict__ in, u16* __restrict__ out,
                                                    int K, int N)
{
  __shared__ u16 t[64][68];
  int k0 = blockIdx.x*64, n0 = blockIdx.y*64;
  int tid = threadIdx.x; int c = tid & 63; int r4 = tid >> 6;
  #pragma unroll
  for (int p = 0; p < 16; p++){
    int kr = r4 + p*4;
    t[kr][c] = f2bf(in[(long long)(k0+kr)*N + n0 + c]);
  }
  __syncthreads();
  #pragma unroll
  for (int p = 0; p < 16; p++){
    int nr = r4 + p*4;
    out[(long long)(n0+nr)*K + k0 + c] = t[c][nr];
  }
}

// ---------------- V transpose: kv[b,key,1280+h*64+d] -> Vt[bh, d, keypad672] ----------------
__global__ __launch_bounds__(256) void kw_vt(const u16* __restrict__ kv, u16* __restrict__ Vt)
{
  int z = blockIdx.x; int kt = blockIdx.y;
  int b = z / 20, hh = z - b*20;
  const u16* src = kv + (long long)b*641*2560 + 1280 + hh*64;
  u16* dst = Vt + (long long)z*64*672;
  __shared__ u16 t[64][68];
  int tid = threadIdx.x; int c = tid & 63; int r4 = tid >> 6;
  #pragma unroll
  for (int p = 0; p < 16; p++){
    int krow = r4 + p*4;
    int key = kt*64 + krow;
    t[krow][c] = (key < 641) ? src[(long long)key*2560 + c] : (u16)0;
  }
  __syncthreads();
  #pragma unroll
  for (int p = 0; p < 16; p++){
    int d = r4 + p*4;
    int key = kt*64 + c;
    if (key < 672) dst[(long long)d*672 + key] = t[c][d];
  }
}

// ---------------- time embedding ----------------
__global__ void kw_timeproj(const float* __restrict__ tstep, float* __restrict__ tproj)
{
  int b = blockIdx.x; int j = threadIdx.x; // 320
  float t = tstep[b];
  int idx = (j < 160) ? j : (j - 160);
  float freq = expf(-9.210340371976184f * (float)idx / 160.0f);
  float a = t * freq;
  tproj[b*320 + j] = (j < 160) ? cosf(a) : sinf(a);
}

// broadcast bias into out[32,N]
__global__ void kw_bias_bcast(const float* __restrict__ bias, float* __restrict__ out, int N)
{
  int b = blockIdx.x; int n = blockIdx.y*256 + threadIdx.x;
  if (n < N) out[(long long)b*N + n] = bias[n];
}

// dense layer, W-read-once k-split: out[b,n] += sum_k in[b,k0+k] * W[k0+k, n]  (atomic)
__global__ __launch_bounds__(256) void kw_mlp2(const float* __restrict__ in, const float* __restrict__ W,
    float* __restrict__ out, int K, int N, int kc)
{
  int n = blockIdx.x*256 + threadIdx.x;
  int k0 = blockIdx.y * kc;
  __shared__ float sbuf[32*160];
  for (int idx = threadIdx.x; idx < 32*kc; idx += 256){
    int b = idx / kc, k = idx - b*kc;
    sbuf[idx] = in[(long long)b*K + k0 + k];
  }
  __syncthreads();
  float acc[32];
  #pragma unroll
  for (int b=0;b<32;b++) acc[b]=0.f;
  const float* wp = W + (long long)k0*N + n;
  for (int k=0;k<kc;k++){
    float wv = wp[(long long)k*N];
    #pragma unroll
    for (int b=0;b<32;b++) acc[b] = fmaf(sbuf[b*kc+k], wv, acc[b]);
  }
  #pragma unroll
  for (int b=0;b<32;b++) atomicAdd(out + (long long)b*N + n, acc[b]);
}

__global__ void kw_silu_ip(float* __restrict__ p, int n)
{
  int i = blockIdx.x*256 + threadIdx.x;
  if (i < n){ float x = p[i]; p[i] = x/(1.f+expf(-x)); }
}

// silu_t = silu(temb); copy temb -> t_emb output
__global__ void kw_post_temb(const float* __restrict__ temb, float* __restrict__ silu_t,
                             float* __restrict__ tout, int n)
{
  int i = blockIdx.x*256 + threadIdx.x;
  if (i < n){
    float x = temb[i];
    silu_t[i] = x/(1.f+expf(-x));
    tout[i] = x;
  }
}

__global__ void kw_ada_init(const float* __restrict__ ada_b, float* __restrict__ ada)
{
  int idx = blockIdx.x*256 + threadIdx.x;
  if (idx < 4*32*5120){
    int i = idx / (32*5120);
    int j = idx % 5120;
    ada[idx] = ada_b[i*5120 + j];
  }
}

__global__ __launch_bounds__(256) void kw_ada(const float* __restrict__ silu_t,
    const float* __restrict__ adaW, float* __restrict__ ada)
{
  int jt = blockIdx.x, i = blockIdx.y, ks = blockIdx.z;
  int tid = threadIdx.x;
  int j = jt*256 + tid;
  __shared__ float sbuf[32][160];
  #pragma unroll
  for (int p = 0; p < 20; p++){
    int idx = tid + p*256;
    int b = idx / 160, k = idx - b*160;
    sbuf[b][k] = silu_t[b*1280 + ks*160 + k];
  }
  __syncthreads();
  float acc[32];
  #pragma unroll
  for (int b=0;b<32;b++) acc[b]=0.f;
  const float* wp = adaW + ((long long)i*1280 + ks*160)*5120 + j;
  for (int k=0;k<160;k++){
    float w = wp[(long long)k*5120];
    #pragma unroll
    for (int b=0;b<32;b++) acc[b] = fmaf(sbuf[b][k], w, acc[b]);
  }
  float* op = ada + (long long)i*32*5120 + j;
  for (int b=0;b<32;b++) atomicAdd(op + (long long)b*5120, acc[b]);
}

__global__ void kw_init_lat(const float* __restrict__ l0, float* __restrict__ lat)
{
  int r = blockIdx.x; int q = r & 63;
  #pragma unroll
  for (int i=0;i<5;i++){
    int c = threadIdx.x + i*256;
    lat[(long long)r*1280 + c] = l0[q*1280 + c];
  }
}

__global__ void kw_cvt(const float* __restrict__ in, u16* __restrict__ out, long long n4)
{
  long long i = ((long long)blockIdx.x*256 + threadIdx.x);
  if (i < n4){
    float4 v = *(const float4*)(in + i*4);
    u32 lo = (u32)f2bf(v.x) | ((u32)f2bf(v.y)<<16);
    u32 hi = (u32)f2bf(v.z) | ((u32)f2bf(v.w)<<16);
    uint2 o; o.x = lo; o.y = hi;
    *(uint2*)(out + i*4) = o;
  }
}

// LN over H=1280, bf16 in -> bf16 out into cat[b*641 + (r%577)]
__global__ __launch_bounds__(256) void kw_ln_x(const u16* __restrict__ h, u16* __restrict__ cat,
    const float* __restrict__ g, const float* __restrict__ bb)
{
  int r = blockIdx.x;
  int batch = r / 577; int rr = r - batch*577;
  const u16* row = h + (long long)r*1280;
  u16* orow = cat + ((long long)batch*641 + rr)*1280;
  int tid = threadIdx.x;
  float v[5]; float s=0.f, s2=0.f;
  #pragma unroll
  for (int i=0;i<5;i++){ float x = bf2f(row[tid+i*256]); v[i]=x; s+=x; s2+=x*x; }
  float2 r2 = block_red_sum2(s, s2);
  float mean = r2.x * (1.f/1280.f);
  float var  = r2.y * (1.f/1280.f) - mean*mean;
  float rstd = rsqrtf(var + 1e-5f);
  #pragma unroll
  for (int i=0;i<5;i++){
    int c = tid+i*256;
    orow[c] = f2bf((v[i]-mean)*rstd*g[c] + bb[c]);
  }
}

// LN over H=1280, f32 in, * (1+sc)+sh, bf16 out (+ optional copy into cat at row b*641+577+q)
__global__ __launch_bounds__(256) void kw_ln_mod(const float* __restrict__ lat, u16* __restrict__ out1,
    u16* __restrict__ cat, const float* __restrict__ g, const float* __restrict__ bb,
    const float* __restrict__ adabase)
{
  int r = blockIdx.x;
  int b = r >> 6, q = r & 63;
  const float* row = lat + (long long)r*1280;
  const float* ab = adabase + (long long)b*5120;
  int tid = threadIdx.x;
  float v[5]; float s=0.f, s2=0.f;
  #pragma unroll
  for (int i=0;i<5;i++){ float x = row[tid+i*256]; v[i]=x; s+=x; s2+=x*x; }
  float2 r2 = block_red_sum2(s, s2);
  float mean = r2.x * (1.f/1280.f);
  float var  = r2.y * (1.f/1280.f) - mean*mean;
  float rstd = rsqrtf(var + 1e-5f);
  #pragma unroll
  for (int i=0;i<5;i++){
    int c = tid+i*256;
    float sh = ab[c], sc = ab[1280+c];
    float y = ((v[i]-mean)*rstd*g[c] + bb[c])*(1.f+sc) + sh;
    u16 o = f2bf(y);
    out1[(long long)r*1280 + c] = o;
    if (cat) cat[((long long)b*641 + 577 + q)*1280 + c] = o;
  }
}

// final LN over O=2432, f32 in -> f32 out
__global__ __launch_bounds__(256) void kw_ln_out(const float* __restrict__ in, float* __restrict__ out,
    const float* __restrict__ g, const float* __restrict__ bb)
{
  int r = blockIdx.x;
  const float* row = in + (long long)r*2432;
  int tid = threadIdx.x;
  float v[10]; float s=0.f, s2=0.f;
  #pragma unroll
  for (int i=0;i<10;i++){
    int c = tid + i*256;
    float x = (c < 2432) ? row[c] : 0.f;
    v[i]=x; s+=x; s2+=x*x;
  }
  float2 r2 = block_red_sum2(s, s2);
  float mean = r2.x * (1.f/2432.f);
  float var  = r2.y * (1.f/2432.f) - mean*mean;
  float rstd = rsqrtf(var + 1e-5f);
  #pragma unroll
  for (int i=0;i<10;i++){
    int c = tid + i*256;
    if (c < 2432) out[(long long)r*2432 + c] = (v[i]-mean)*rstd*g[c] + bb[c];
  }
}

// ---------------- host ----------------
static inline void launch_gemm(hipStream_t s, const u16* A, const u16* B, void* C,
    int M, int Nclamp, int Nout, int K, int lda, int ldb, int ldc,
    int nz, int zdiv, long long sA1, long long sA2, long long sB1, long long sB2,
    long long sC1, long long sC2, int flags,
    const float* bias = nullptr, const float* temb = nullptr, int rowdiv = 1,
    const float* res = nullptr, int ldres = 0)
{
  dim3 g((Nout+127)/128, (M+127)/128, nz);   // x = N-tiles (fast): blocks share A tile, stream B
  kw_gemm<<<g, dim3(256), 0, s>>>(A,B,C,M,Nclamp,Nout,K,lda,ldb,ldc,
      sA1,sA2,sB1,sB2,sC1,sC2,zdiv,flags,bias,temb,rowdiv,res,ldres);
}

extern "C" void kernel_launch(void* const* d_in, const int* in_sizes, int n_in,
                              void* d_out, int out_size, void* d_ws, size_t ws_size,
                              hipStream_t stream)
{
  const float* x         = (const float*)d_in[0];
  const float* timestep  = (const float*)d_in[1];
  const float* latents0  = (const float*)d_in[2];
  const float* proj_in_W = (const float*)d_in[3];
  const float* proj_in_b = (const float*)d_in[4];
  const float* te1_W     = (const float*)d_in[5];
  const float* te1_b     = (const float*)d_in[6];
  const float* te2_W     = (const float*)d_in[7];
  const float* te2_b     = (const float*)d_in[8];
  const float* ln0_g     = (const float*)d_in[9];
  const float* ln0_b     = (const float*)d_in[10];
  const float* ln1_g     = (const float*)d_in[11];
  const float* ln1_b     = (const float*)d_in[12];
  const float* Wq        = (const float*)d_in[13];
  const float* Wkv       = (const float*)d_in[14];
  const float* Wo        = (const float*)d_in[15];
  const float* ada_W     = (const float*)d_in[16];
  const float* ada_b     = (const float*)d_in[17];
  const float* lnada_g   = (const float*)d_in[18];
  const float* lnada_b   = (const float*)d_in[19];
  const float* Wff1      = (const float*)d_in[20];
  const float* Wff2      = (const float*)d_in[21];
  const float* proj_out_W= (const float*)d_in[22];
  const float* proj_out_b= (const float*)d_in[23];
  const float* norm_out_g= (const float*)d_in[24];
  const float* norm_out_b= (const float*)d_in[25];
  float* out = (float*)d_out;

  const long long MX = 18464;   // B*N
  const long long MC = 20512;   // B*641

  char* w = (char*)d_ws; size_t off = 0;
  auto alloc = [&](size_t bytes)->void*{ void* p = w + off; off += (bytes + 255) & ~(size_t)255; return p; };

  float* tproj  = (float*)alloc(32*320*4);
  float* hidden = (float*)alloc(32*1280*4);
  float* temb   = (float*)alloc(32*1280*4);
  float* silu_t = (float*)alloc(32*1280*4);
  float* ada    = (float*)alloc(4*32*5120*4);
  u16*  h    = (u16*)alloc(MX*1280*2);
  u16*  cat  = (u16*)alloc(MC*1280*2);
  u16*  lm   = (u16*)alloc(2048*1280*2);
  u16*  lm2  = (u16*)alloc(2048*1280*2);
  u16*  qb   = (u16*)alloc(2048*1280*2);
  u16*  att  = (u16*)alloc(2048*1280*2);
  float* lat = (float*)alloc(2048*1280*4);
  u16*  kvb  = (u16*)alloc(MC*2560*2);
  u16*  Vt   = (u16*)alloc((long long)640*64*672*2);
  u16*  WT_pi  = (u16*)alloc(1280*1152*2);
  u16*  WT_po  = (u16*)alloc((long long)2432*1280*2);
  u16*  WqT    = (u16*)alloc(1280*1280*2);
  u16*  WkvT   = (u16*)alloc(2560*1280*2);
  u16*  WoT    = (u16*)alloc(1280*1280*2);
  u16*  Wff1T  = (u16*)alloc((long long)5120*1280*2);
  u16*  Wff2T  = (u16*)alloc((long long)1280*5120*2);
  // overlaid region: x_bf16 -> ffh -> proj_out pre-LN
  char* R = (char*)alloc((long long)2048*5120*2 + 4096);
  u16*  xbf    = (u16*)R;
  u16*  ffh    = (u16*)R;
  float* po    = (float*)R;

  if (off > ws_size) return; // workspace too small -> fail loudly via wrong output

  // time embedding MLP (f32, exact path: t_emb is output 1)
  kw_timeproj<<<dim3(32), dim3(320), 0, stream>>>(timestep, tproj);
  kw_bias_bcast<<<dim3(32,5), dim3(256), 0, stream>>>(te1_b, hidden, 1280);
  kw_mlp2<<<dim3(5,4), dim3(256), 0, stream>>>(tproj, te1_W, hidden, 320, 1280, 80);
  kw_silu_ip<<<dim3(160), dim3(256), 0, stream>>>(hidden, 32*1280);
  kw_bias_bcast<<<dim3(32,5), dim3(256), 0, stream>>>(te2_b, temb, 1280);
  kw_mlp2<<<dim3(5,8), dim3(256), 0, stream>>>(hidden, te2_W, temb, 1280, 1280, 160);
  kw_post_temb<<<dim3(160), dim3(256), 0, stream>>>(temb, silu_t, out + (long long)2048*2432, 32*1280);

  // adaLN embeddings for all 4 blocks
  kw_ada_init<<<dim3(2560), dim3(256), 0, stream>>>(ada_b, ada);
  kw_ada<<<dim3(20,4,8), dim3(256), 0, stream>>>(silu_t, ada_W, ada);

  // proj_in
  kw_cvt<<<dim3((unsigned)((MX*1152/4 + 255)/256)), dim3(256), 0, stream>>>(x, xbf, MX*1152/4);
  kw_transpose<<<dim3(18,20), dim3(256), 0, stream>>>(proj_in_W, WT_pi, 1152, 1280);
  launch_gemm(stream, xbf, WT_pi, h, (int)MX, 1280, 1280, 1152, 1152, 1152, 1280,
              1, 1, 0,0,0,0,0,0, 1|2|16, proj_in_b, temb, 577);

  kw_init_lat<<<dim3(2048), dim3(256), 0, stream>>>(latents0, lat);
  kw_transpose<<<dim3(20,38), dim3(256), 0, stream>>>(proj_out_W, WT_po, 1280, 2432);

  for (int i = 0; i < 4; i++){
    kw_transpose<<<dim3(20,20), dim3(256), 0, stream>>>(Wq   + (long long)i*1280*1280, WqT,   1280, 1280);
    kw_transpose<<<dim3(20,40), dim3(256), 0, stream>>>(Wkv  + (long long)i*1280*2560, WkvT,  1280, 2560);
    kw_transpose<<<dim3(20,20), dim3(256), 0, stream>>>(Wo   + (long long)i*1280*1280, WoT,   1280, 1280);
    kw_transpose<<<dim3(20,80), dim3(256), 0, stream>>>(Wff1 + (long long)i*1280*5120, Wff1T, 1280, 5120);
    kw_transpose<<<dim3(80,20), dim3(256), 0, stream>>>(Wff2 + (long long)i*5120*1280, Wff2T, 5120, 1280);

    kw_ln_x<<<dim3((unsigned)MX), dim3(256), 0, stream>>>(h, cat, ln0_g + i*1280, ln0_b + i*1280);
    kw_ln_mod<<<dim3(2048), dim3(256), 0, stream>>>(lat, lm, cat, ln1_g + i*1280, ln1_b + i*1280,
                                                    ada + (long long)i*32*5120 + 0);
    // q / kv projections
    launch_gemm(stream, lm,  WqT,  qb,  2048, 1280, 1280, 1280, 1280, 1280, 1280, 1, 1, 0,0,0,0,0,0, 16);
    launch_gemm(stream, cat, WkvT, kvb, (int)MC, 2560, 2560, 1280, 1280, 1280, 2560, 1, 1, 0,0,0,0,0,0, 16);
    // fused flash attention
    kw_vt<<<dim3(640,11), dim3(256), 0, stream>>>(kvb, Vt);
    kw_flash<<<dim3(640), dim3(256), 0, stream>>>(qb, kvb, Vt, att);
    // out projection + residual (in-place on lat)
    launch_gemm(stream, att, WoT, lat, 2048, 1280, 1280, 1280, 1280, 1280, 1280,
                1, 1, 0,0,0,0,0,0, 4, nullptr, nullptr, 1, lat, 1280);
    // MLP
    kw_ln_mod<<<dim3(2048), dim3(256), 0, stream>>>(lat, lm2, nullptr, lnada_g + i*1280, lnada_b + i*1280,
                                                    ada + (long long)i*32*5120 + 2560);
    launch_gemm(stream, lm2, Wff1T, ffh, 2048, 5120, 5120, 1280, 1280, 1280, 5120,
                1, 1, 0,0,0,0,0,0, 8|16);
    launch_gemm(stream, ffh, Wff2T, lat, 2048, 1280, 1280, 5120, 5120, 5120, 1280,
                1, 1, 0,0,0,0,0,0, 4, nullptr, nullptr, 1, lat, 1280);
  }

  // proj_out + final LN
  kw_cvt<<<dim3(2560), dim3(256), 0, stream>>>(lat, lm, 2048*1280/4);
  launch_gemm(stream, lm, WT_po, po, 2048, 2432, 2432, 1280, 1280, 1280, 2432,
              1, 1, 0,0,0,0,0,0, 1, proj_out_b);
  kw_ln_out<<<dim3(2048), dim3(256), 0, stream>>>(po, out, norm_out_g, norm_out_b);
}